// Round 1
// baseline (455.173 us; speedup 1.0000x reference)
//
#include <hip/hip_runtime.h>
#include <math.h>

#define BB 8
#define CC 256
#define HH 64
#define WW 64
#define H2 32
#define W2 32
#define NPIX (BB*HH*WW)
#define EPSV 1e-5f

// ---------------- K1: bilinear 2x upsample of x2, |x21-x22|, repeat -> guide NHWC ----------------
// grid: B * H * (C/64) = 8*64*4 = 2048 blocks, 256 threads
__global__ __launch_bounds__(256) void k1_guide(const float* __restrict__ x2,
                                                float* __restrict__ guide) {
    int blk = blockIdx.x;
    int c0 = (blk & 3) * 64;
    int y  = (blk >> 2) & 63;
    int b  = blk >> 8;
    int bb = b & 3;
    __shared__ float tile[64][65];
    int t = threadIdx.x;
    int x = t & 63;

    float sx = 0.5f * x - 0.25f;
    float sy = 0.5f * y - 0.25f;
    float fx0 = floorf(sx), fy0 = floorf(sy);
    float wx = sx - fx0, wy = sy - fy0;
    int jx0 = (int)fx0, jy0 = (int)fy0;
    int ix0 = max(0, min(W2 - 1, jx0));
    int ix1 = max(0, min(W2 - 1, jx0 + 1));
    int iy0 = max(0, min(H2 - 1, jy0));
    int iy1 = max(0, min(H2 - 1, jy0 + 1));
    float w00 = (1.f - wy) * (1.f - wx), w01 = (1.f - wy) * wx;
    float w10 = wy * (1.f - wx), w11 = wy * wx;
    int o00 = iy0 * W2 + ix0, o01 = iy0 * W2 + ix1;
    int o10 = iy1 * W2 + ix0, o11 = iy1 * W2 + ix1;

    int cl = t >> 6;   // 0..3
    #pragma unroll
    for (int it = 0; it < 16; ++it) {
        int c = cl + it * 4;           // 0..63
        const float* p1 = x2 + (size_t)((bb * CC + c0 + c) * H2) * W2;
        const float* p2 = x2 + (size_t)(((bb + 4) * CC + c0 + c) * H2) * W2;
        float v1 = w00 * p1[o00] + w01 * p1[o01] + w10 * p1[o10] + w11 * p1[o11];
        float v2 = w00 * p2[o00] + w01 * p2[o01] + w10 * p2[o10] + w11 * p2[o11];
        tile[c][x] = fabsf(v1 - v2);
    }
    __syncthreads();
    #pragma unroll
    for (int it = 0; it < 16; ++it) {
        int idx = t + it * 256;
        int cw = idx & 63;
        int xw = idx >> 6;
        guide[(size_t)((b * HH + y) * WW + xw) * CC + c0 + cw] = tile[cw][xw];
    }
}

// ---------------- K2: dwconv3x3 + LN + GELU + offset/mask heads + softmax ----------------
// grid: NPIX blocks, 256 threads (thread = channel)
__global__ __launch_bounds__(256) void k2_offmask(const float* __restrict__ guide,
        const float* __restrict__ dw_w, const float* __restrict__ dw_b,
        const float* __restrict__ ln_g, const float* __restrict__ ln_b,
        const float* __restrict__ off_w, const float* __restrict__ off_b,
        const float* __restrict__ mask_w, const float* __restrict__ mask_b,
        float* __restrict__ offmask) {
    int n = blockIdx.x;
    int x = n & 63, y = (n >> 6) & 63, b = n >> 12;
    int c = threadIdx.x;

    float v = dw_b[c];
    #pragma unroll
    for (int dy = -1; dy <= 1; ++dy) {
        #pragma unroll
        for (int dx = -1; dx <= 1; ++dx) {
            int yy = y + dy, xx = x + dx;
            if (yy >= 0 && yy < HH && xx >= 0 && xx < WW) {
                v += guide[(size_t)((b * HH + yy) * WW + xx) * CC + c]
                   * dw_w[((dy + 1) * 3 + (dx + 1)) * CC + c];
            }
        }
    }
    // LayerNorm over C
    float s1 = v, s2 = v * v;
    #pragma unroll
    for (int off = 32; off; off >>= 1) {
        s1 += __shfl_xor(s1, off);
        s2 += __shfl_xor(s2, off);
    }
    __shared__ float red[8];
    int wid = c >> 6, lane = c & 63;
    if (lane == 0) { red[wid] = s1; red[wid + 4] = s2; }
    __syncthreads();
    float t1 = red[0] + red[1] + red[2] + red[3];
    float t2 = red[4] + red[5] + red[6] + red[7];
    float mean = t1 * (1.0f / CC);
    float var  = t2 * (1.0f / CC) - mean * mean;
    v = (v - mean) * rsqrtf(var + EPSV) * ln_g[c] + ln_b[c];
    // GELU (tanh approx, JAX default)
    v = 0.5f * v * (1.0f + tanhf(0.7978845608028654f * (v + 0.044715f * v * v * v)));

    __shared__ float feat[CC];
    feat[c] = v;
    __shared__ float outv[27];
    __syncthreads();

    for (int j = wid; j < 27; j += 4) {
        float p = 0.f;
        #pragma unroll
        for (int e = 0; e < 4; ++e) {
            int cidx = lane + 64 * e;
            float wv = (j < 18) ? off_w[cidx * 18 + j] : mask_w[cidx * 9 + (j - 18)];
            p += feat[cidx] * wv;
        }
        #pragma unroll
        for (int off = 32; off; off >>= 1) p += __shfl_xor(p, off);
        if (lane == 0) outv[j] = p + ((j < 18) ? off_b[j] : mask_b[j - 18]);
    }
    __syncthreads();
    __shared__ float sm[9];
    if (c == 0) {
        float mx = outv[18];
        #pragma unroll
        for (int k = 1; k < 9; ++k) mx = fmaxf(mx, outv[18 + k]);
        float e9[9]; float ssum = 0.f;
        #pragma unroll
        for (int k = 0; k < 9; ++k) { e9[k] = expf(outv[18 + k] - mx); ssum += e9[k]; }
        float inv = 1.0f / ssum;
        #pragma unroll
        for (int k = 0; k < 9; ++k) sm[k] = e9[k] * inv;
    }
    __syncthreads();
    if (c < 18)       offmask[(size_t)n * 32 + c] = outv[c];
    else if (c < 27)  offmask[(size_t)n * 32 + c] = sm[c - 18];
}

// ---------------- K3: x_proj = NHWC(x1) @ in_w + in_b ----------------
// grid: (NPIX/64) * (C/64) = 512*4 = 2048 blocks, 256 threads, 64x64 tile, 4x4 microtile
__global__ __launch_bounds__(256) void k3_inproj(const float* __restrict__ x1,
        const float* __restrict__ in_w, const float* __restrict__ in_b,
        float* __restrict__ xproj) {
    int bn = blockIdx.x & 3;
    int bm = blockIdx.x >> 2;        // pixel-row tile: (b,y), covers x=0..63
    int n0 = bn * 64;
    int y = bm & 63, b = bm >> 6;
    __shared__ float As[32 * 64];    // [k][m]
    __shared__ float Bs[32 * 64];    // [k][n]
    int t = threadIdx.x;
    int tx = t & 15, ty = t >> 4;
    float acc[4][4] = {};

    for (int k0 = 0; k0 < CC; k0 += 32) {
        #pragma unroll
        for (int i = 0; i < 8; ++i) {
            int idx = t + i * 256;
            int k = idx >> 6, xx = idx & 63;
            As[k * 64 + xx] = x1[(size_t)((b * CC + k0 + k) * HH + y) * WW + xx];
        }
        #pragma unroll
        for (int i = 0; i < 8; ++i) {
            int idx = t + i * 256;
            int k = idx >> 6, nn = idx & 63;
            Bs[k * 64 + nn] = in_w[(size_t)(k0 + k) * CC + n0 + nn];
        }
        __syncthreads();
        #pragma unroll
        for (int kk = 0; kk < 32; ++kk) {
            float4 a4 = *(const float4*)(As + kk * 64 + ty * 4);
            float4 b4 = *(const float4*)(Bs + kk * 64 + tx * 4);
            float av[4] = {a4.x, a4.y, a4.z, a4.w};
            float bv[4] = {b4.x, b4.y, b4.z, b4.w};
            #pragma unroll
            for (int i = 0; i < 4; ++i)
                #pragma unroll
                for (int j = 0; j < 4; ++j)
                    acc[i][j] = fmaf(av[i], bv[j], acc[i][j]);
        }
        __syncthreads();
    }
    float4 bias = *(const float4*)(in_b + n0 + tx * 4);
    float bv[4] = {bias.x, bias.y, bias.z, bias.w};
    #pragma unroll
    for (int i = 0; i < 4; ++i) {
        int m = bm * 64 + ty * 4 + i;
        float4 o;
        o.x = acc[i][0] + bv[0];
        o.y = acc[i][1] + bv[1];
        o.z = acc[i][2] + bv[2];
        o.w = acc[i][3] + bv[3];
        *(float4*)(xproj + (size_t)m * CC + n0 + tx * 4) = o;
    }
}

// ---------------- K4: deformable bilinear sampling ----------------
// grid: NPIX blocks, 256 threads (thread = channel)
__global__ __launch_bounds__(256) void k4_sample(const float* __restrict__ xproj,
        const float* __restrict__ offmask, float* __restrict__ accb) {
    int n = blockIdx.x;
    int x = n & 63, y = (n >> 6) & 63, b = n >> 12;
    int t = threadIdx.x;
    __shared__ int   s_idx[9][4];
    __shared__ float s_w[9][4];
    if (t < 9) {
        int k = t;
        float dx = offmask[(size_t)n * 32 + 2 * k];
        float dy = offmask[(size_t)n * 32 + 2 * k + 1];
        float m  = offmask[(size_t)n * 32 + 18 + k];
        float py = (float)y + (float)(k / 3 - 1) + dy;
        float px = (float)x + (float)(k % 3 - 1) + dx;
        float y0f = floorf(py), x0f = floorf(px);
        float wy = py - y0f, wx = px - x0f;
        int y0 = (int)y0f, x0 = (int)x0f;
        int y1 = y0 + 1, x1 = x0 + 1;
        float vy0 = (y0 >= 0 && y0 < HH) ? 1.f : 0.f;
        float vy1 = (y1 >= 0 && y1 < HH) ? 1.f : 0.f;
        float vx0 = (x0 >= 0 && x0 < WW) ? 1.f : 0.f;
        float vx1 = (x1 >= 0 && x1 < WW) ? 1.f : 0.f;
        int yc0 = max(0, min(HH - 1, y0)), yc1 = max(0, min(HH - 1, y1));
        int xc0 = max(0, min(WW - 1, x0)), xc1 = max(0, min(WW - 1, x1));
        int base = b * HH * WW;
        s_idx[k][0] = (base + yc0 * WW + xc0) * CC;
        s_idx[k][1] = (base + yc0 * WW + xc1) * CC;
        s_idx[k][2] = (base + yc1 * WW + xc0) * CC;
        s_idx[k][3] = (base + yc1 * WW + xc1) * CC;
        s_w[k][0] = m * (1.f - wy) * (1.f - wx) * vy0 * vx0;
        s_w[k][1] = m * (1.f - wy) * wx * vy0 * vx1;
        s_w[k][2] = m * wy * (1.f - wx) * vy1 * vx0;
        s_w[k][3] = m * wy * wx * vy1 * vx1;
    }
    __syncthreads();
    int c = t;
    float a = 0.f;
    #pragma unroll
    for (int k = 0; k < 9; ++k) {
        a += s_w[k][0] * xproj[s_idx[k][0] + c]
           + s_w[k][1] * xproj[s_idx[k][1] + c]
           + s_w[k][2] * xproj[s_idx[k][2] + c]
           + s_w[k][3] * xproj[s_idx[k][3] + c];
    }
    accb[(size_t)n * CC + c] = a;
}

// ---------------- K5: y = acc @ out_w + out_b -> BN -> ReLU -> +x1, NCHW out ----------------
// grid: 512*4 = 2048 blocks, 256 threads
__global__ __launch_bounds__(256) void k5_outproj(const float* __restrict__ accb,
        const float* __restrict__ out_w, const float* __restrict__ out_b,
        const float* __restrict__ bn_g, const float* __restrict__ bn_b,
        const float* __restrict__ bn_mean, const float* __restrict__ bn_var,
        const float* __restrict__ x1, float* __restrict__ out) {
    int bn = blockIdx.x & 3;
    int bm = blockIdx.x >> 2;
    int n0 = bn * 64;
    int y = bm & 63, b = bm >> 6;
    __shared__ float smem[32 * 68 + 32 * 64];   // As[32][68] | Bs[32][64]; reused as Lo[64][65]
    float* As = smem;
    float* Bs = smem + 32 * 68;
    int t = threadIdx.x;
    int tx = t & 15, ty = t >> 4;
    float acc[4][4] = {};

    for (int k0 = 0; k0 < CC; k0 += 32) {
        #pragma unroll
        for (int i = 0; i < 8; ++i) {
            int idx = t + i * 256;
            int mm = idx >> 5, kk = idx & 31;
            As[kk * 68 + mm] = accb[(size_t)(bm * 64 + mm) * CC + k0 + kk];
        }
        #pragma unroll
        for (int i = 0; i < 8; ++i) {
            int idx = t + i * 256;
            int k = idx >> 6, nn = idx & 63;
            Bs[k * 64 + nn] = out_w[(size_t)(k0 + k) * CC + n0 + nn];
        }
        __syncthreads();
        #pragma unroll
        for (int kk = 0; kk < 32; ++kk) {
            float4 a4 = *(const float4*)(As + kk * 68 + ty * 4);
            float4 b4 = *(const float4*)(Bs + kk * 64 + tx * 4);
            float av[4] = {a4.x, a4.y, a4.z, a4.w};
            float bv[4] = {b4.x, b4.y, b4.z, b4.w};
            #pragma unroll
            for (int i = 0; i < 4; ++i)
                #pragma unroll
                for (int j = 0; j < 4; ++j)
                    acc[i][j] = fmaf(av[i], bv[j], acc[i][j]);
        }
        __syncthreads();
    }
    // bounce via LDS for coalesced NCHW store; fuse bias+BN+ReLU+residual
    float* Lo = smem;   // [64][65]: Lo[m][co]
    #pragma unroll
    for (int i = 0; i < 4; ++i)
        #pragma unroll
        for (int j = 0; j < 4; ++j)
            Lo[(ty * 4 + i) * 65 + tx * 4 + j] = acc[i][j];
    __syncthreads();
    #pragma unroll
    for (int it = 0; it < 16; ++it) {
        int idx = t + it * 256;
        int xx = idx & 63;
        int cw = idx >> 6;            // 0..63
        int co = n0 + cw;
        float val = Lo[xx * 65 + cw] + out_b[co];
        float scale = bn_g[co] * rsqrtf(bn_var[co] + EPSV);
        float shift = bn_b[co] - bn_mean[co] * scale;
        val = fmaxf(val * scale + shift, 0.f);
        size_t g = (size_t)((b * CC + co) * HH + y) * WW + xx;
        out[g] = val + x1[g];
    }
}

extern "C" void kernel_launch(void* const* d_in, const int* in_sizes, int n_in,
                              void* d_out, int out_size, void* d_ws, size_t ws_size,
                              hipStream_t stream) {
    const float* x1     = (const float*)d_in[0];
    const float* x2     = (const float*)d_in[1];
    const float* dw_w   = (const float*)d_in[2];
    const float* dw_b   = (const float*)d_in[3];
    const float* ln_g   = (const float*)d_in[4];
    const float* ln_b   = (const float*)d_in[5];
    const float* off_w  = (const float*)d_in[6];
    const float* off_b  = (const float*)d_in[7];
    const float* mask_w = (const float*)d_in[8];
    const float* mask_b = (const float*)d_in[9];
    const float* in_w   = (const float*)d_in[10];
    const float* in_b   = (const float*)d_in[11];
    const float* out_w  = (const float*)d_in[12];
    const float* out_b  = (const float*)d_in[13];
    const float* bn_g   = (const float*)d_in[14];
    const float* bn_b   = (const float*)d_in[15];
    const float* bn_mean= (const float*)d_in[16];
    const float* bn_var = (const float*)d_in[17];
    float* out = (float*)d_out;

    float* ws      = (float*)d_ws;
    float* guide   = ws;                          // NPIX*C floats (33.5 MB)
    float* xproj   = ws + (size_t)NPIX * CC;      // NPIX*C floats (33.5 MB)
    float* offmask = ws + (size_t)2 * NPIX * CC;  // NPIX*32 floats (4 MB)
    float* accb    = guide;                       // guide dead after K2 -> alias

    hipLaunchKernelGGL(k1_guide,   dim3(2048), dim3(256), 0, stream, x2, guide);
    hipLaunchKernelGGL(k2_offmask, dim3(NPIX), dim3(256), 0, stream, guide, dw_w, dw_b,
                       ln_g, ln_b, off_w, off_b, mask_w, mask_b, offmask);
    hipLaunchKernelGGL(k3_inproj,  dim3(2048), dim3(256), 0, stream, x1, in_w, in_b, xproj);
    hipLaunchKernelGGL(k4_sample,  dim3(NPIX), dim3(256), 0, stream, xproj, offmask, accb);
    hipLaunchKernelGGL(k5_outproj, dim3(2048), dim3(256), 0, stream, accb, out_w, out_b,
                       bn_g, bn_b, bn_mean, bn_var, x1, out);
}

// Round 2
// 293.081 us; speedup vs baseline: 1.5531x; 1.5531x over previous
//
#include <hip/hip_runtime.h>
#include <math.h>

#define BB 8
#define CC 256
#define HH 64
#define WW 64
#define H2 32
#define W2 32
#define NPIX (BB*HH*WW)
#define EPSV 1e-5f

// ---------------- K1: bilinear 2x upsample of x2, |x21-x22|, repeat -> guide NHWC ----------------
// grid: B * H * (C/64) = 8*64*4 = 2048 blocks, 256 threads
__global__ __launch_bounds__(256) void k1_guide(const float* __restrict__ x2,
                                                float* __restrict__ guide) {
    int blk = blockIdx.x;
    int c0 = (blk & 3) * 64;
    int y  = (blk >> 2) & 63;
    int b  = blk >> 8;
    int bb = b & 3;
    __shared__ float tile[64][65];
    int t = threadIdx.x;
    int x = t & 63;

    float sx = 0.5f * x - 0.25f;
    float sy = 0.5f * y - 0.25f;
    float fx0 = floorf(sx), fy0 = floorf(sy);
    float wx = sx - fx0, wy = sy - fy0;
    int jx0 = (int)fx0, jy0 = (int)fy0;
    int ix0 = max(0, min(W2 - 1, jx0));
    int ix1 = max(0, min(W2 - 1, jx0 + 1));
    int iy0 = max(0, min(H2 - 1, jy0));
    int iy1 = max(0, min(H2 - 1, jy0 + 1));
    float w00 = (1.f - wy) * (1.f - wx), w01 = (1.f - wy) * wx;
    float w10 = wy * (1.f - wx), w11 = wy * wx;
    int o00 = iy0 * W2 + ix0, o01 = iy0 * W2 + ix1;
    int o10 = iy1 * W2 + ix0, o11 = iy1 * W2 + ix1;

    int cl = t >> 6;   // 0..3
    #pragma unroll
    for (int it = 0; it < 16; ++it) {
        int c = cl + it * 4;           // 0..63
        const float* p1 = x2 + (size_t)((bb * CC + c0 + c) * H2) * W2;
        const float* p2 = x2 + (size_t)(((bb + 4) * CC + c0 + c) * H2) * W2;
        float v1 = w00 * p1[o00] + w01 * p1[o01] + w10 * p1[o10] + w11 * p1[o11];
        float v2 = w00 * p2[o00] + w01 * p2[o01] + w10 * p2[o10] + w11 * p2[o11];
        tile[c][x] = fabsf(v1 - v2);
    }
    __syncthreads();
    #pragma unroll
    for (int it = 0; it < 16; ++it) {
        int idx = t + it * 256;
        int cw = idx & 63;
        int xw = idx >> 6;
        guide[(size_t)((b * HH + y) * WW + xw) * CC + c0 + cw] = tile[cw][xw];
    }
}

// ---------------- K2a: dwconv3x3 + LN + GELU -> feat NHWC ----------------
// grid: NPIX blocks, 256 threads (thread = channel)
__global__ __launch_bounds__(256) void k2a_feat(const float* __restrict__ guide,
        const float* __restrict__ dw_w, const float* __restrict__ dw_b,
        const float* __restrict__ ln_g, const float* __restrict__ ln_b,
        float* __restrict__ feat) {
    int n = blockIdx.x;
    int x = n & 63, y = (n >> 6) & 63, b = n >> 12;
    int c = threadIdx.x;

    float v = dw_b[c];
    #pragma unroll
    for (int dy = -1; dy <= 1; ++dy) {
        #pragma unroll
        for (int dx = -1; dx <= 1; ++dx) {
            int yy = y + dy, xx = x + dx;
            if (yy >= 0 && yy < HH && xx >= 0 && xx < WW) {
                v += guide[(size_t)((b * HH + yy) * WW + xx) * CC + c]
                   * dw_w[((dy + 1) * 3 + (dx + 1)) * CC + c];
            }
        }
    }
    // LayerNorm over C
    float s1 = v, s2 = v * v;
    #pragma unroll
    for (int off = 32; off; off >>= 1) {
        s1 += __shfl_xor(s1, off);
        s2 += __shfl_xor(s2, off);
    }
    __shared__ float red[8];
    int wid = c >> 6, lane = c & 63;
    if (lane == 0) { red[wid] = s1; red[wid + 4] = s2; }
    __syncthreads();
    float t1 = red[0] + red[1] + red[2] + red[3];
    float t2 = red[4] + red[5] + red[6] + red[7];
    float mean = t1 * (1.0f / CC);
    float var  = t2 * (1.0f / CC) - mean * mean;
    v = (v - mean) * rsqrtf(var + EPSV) * ln_g[c] + ln_b[c];
    // GELU tanh-approx via sigmoid identity: 0.5x(1+tanh(u)) = x * sigmoid(2u)
    float u2 = 1.5957691216057308f * (v + 0.044715f * v * v * v);   // 2*sqrt(2/pi)*(...)
    v = v * __frcp_rn(1.0f + __expf(-u2));
    feat[(size_t)n * CC + c] = v;
}

// ---------------- K2b: offmask = feat @ [off_w|mask_w] + bias, softmax(mask) ----------------
// grid: NPIX/64 = 512 blocks, 256 threads. Tile: M=64 pixels, N=32 (27 used), K=256.
__global__ __launch_bounds__(256) void k2b_heads(const float* __restrict__ feat,
        const float* __restrict__ off_w, const float* __restrict__ off_b,
        const float* __restrict__ mask_w, const float* __restrict__ mask_b,
        float* __restrict__ offmask) {
    int p0 = blockIdx.x * 64;
    int t = threadIdx.x;
    __shared__ float Wc[CC * 32];       // [k][j], j 0..17 off, 18..26 mask, 27..31 zero
    __shared__ float As[64 * 36];       // [m][k] padded; reused as O[64][36]

    // stage weights once (tiny, one-time strided reads)
    for (int idx = t; idx < CC * 32; idx += 256) {
        int k = idx >> 5, j = idx & 31;
        float w = 0.f;
        if (j < 18)      w = off_w[k * 18 + j];
        else if (j < 27) w = mask_w[k * 9 + (j - 18)];
        Wc[idx] = w;
    }

    int tx = t & 7;          // n0 = 4*tx
    int ty = t >> 3;         // m0 = 2*ty
    int n0 = tx * 4, m0 = ty * 2;
    float acc[2][4] = {};

    for (int k0 = 0; k0 < CC; k0 += 32) {
        #pragma unroll
        for (int i = 0; i < 2; ++i) {
            int q = t + i * 256;         // 0..511 float4 slots
            int m = q >> 3;              // 0..63
            int kq = (q & 7) * 4;        // 0,4,..,28
            float4 v4 = *(const float4*)(feat + (size_t)(p0 + m) * CC + k0 + kq);
            *(float4*)(As + m * 36 + kq) = v4;
        }
        __syncthreads();
        #pragma unroll
        for (int kk = 0; kk < 32; ++kk) {
            float a0 = As[m0 * 36 + kk];
            float a1 = As[(m0 + 1) * 36 + kk];
            const float* bp = Wc + (k0 + kk) * 32 + n0;
            #pragma unroll
            for (int ni = 0; ni < 4; ++ni) {
                float bw = bp[ni];
                acc[0][ni] = fmaf(a0, bw, acc[0][ni]);
                acc[1][ni] = fmaf(a1, bw, acc[1][ni]);
            }
        }
        __syncthreads();
    }

    // add bias, park in LDS (reuse As as O[64][36])
    float* O = As;
    #pragma unroll
    for (int ni = 0; ni < 4; ++ni) {
        int j = n0 + ni;
        float bias = (j < 18) ? off_b[j] : ((j < 27) ? mask_b[j - 18] : 0.f);
        O[m0 * 36 + j] = acc[0][ni] + bias;
        O[(m0 + 1) * 36 + j] = acc[1][ni] + bias;
    }
    __syncthreads();
    // per-pixel softmax over cols 18..26, 64 threads in parallel
    if (t < 64) {
        float* row = O + t * 36 + 18;
        float mx = row[0];
        #pragma unroll
        for (int k = 1; k < 9; ++k) mx = fmaxf(mx, row[k]);
        float e9[9], ssum = 0.f;
        #pragma unroll
        for (int k = 0; k < 9; ++k) { e9[k] = __expf(row[k] - mx); ssum += e9[k]; }
        float inv = __frcp_rn(ssum);
        #pragma unroll
        for (int k = 0; k < 9; ++k) row[k] = e9[k] * inv;
    }
    __syncthreads();
    // coalesced write: 64 pixels x 32 cols
    #pragma unroll
    for (int i = 0; i < 8; ++i) {
        int idx = t + i * 256;
        int p = idx >> 5, j = idx & 31;
        offmask[(size_t)(p0 + p) * 32 + j] = O[p * 36 + j];
    }
}

// ---------------- K3: x_proj = NHWC(x1) @ in_w + in_b ----------------
// grid: (NPIX/64) * (C/64) = 512*4 = 2048 blocks, 256 threads, 64x64 tile, 4x4 microtile
__global__ __launch_bounds__(256) void k3_inproj(const float* __restrict__ x1,
        const float* __restrict__ in_w, const float* __restrict__ in_b,
        float* __restrict__ xproj) {
    int bn = blockIdx.x & 3;
    int bm = blockIdx.x >> 2;        // pixel-row tile: (b,y), covers x=0..63
    int n0 = bn * 64;
    int y = bm & 63, b = bm >> 6;
    __shared__ float As[32 * 64];    // [k][m]
    __shared__ float Bs[32 * 64];    // [k][n]
    int t = threadIdx.x;
    int tx = t & 15, ty = t >> 4;
    float acc[4][4] = {};

    for (int k0 = 0; k0 < CC; k0 += 32) {
        #pragma unroll
        for (int i = 0; i < 8; ++i) {
            int idx = t + i * 256;
            int k = idx >> 6, xx = idx & 63;
            As[k * 64 + xx] = x1[(size_t)((b * CC + k0 + k) * HH + y) * WW + xx];
        }
        #pragma unroll
        for (int i = 0; i < 8; ++i) {
            int idx = t + i * 256;
            int k = idx >> 6, nn = idx & 63;
            Bs[k * 64 + nn] = in_w[(size_t)(k0 + k) * CC + n0 + nn];
        }
        __syncthreads();
        #pragma unroll
        for (int kk = 0; kk < 32; ++kk) {
            float4 a4 = *(const float4*)(As + kk * 64 + ty * 4);
            float4 b4 = *(const float4*)(Bs + kk * 64 + tx * 4);
            float av[4] = {a4.x, a4.y, a4.z, a4.w};
            float bv[4] = {b4.x, b4.y, b4.z, b4.w};
            #pragma unroll
            for (int i = 0; i < 4; ++i)
                #pragma unroll
                for (int j = 0; j < 4; ++j)
                    acc[i][j] = fmaf(av[i], bv[j], acc[i][j]);
        }
        __syncthreads();
    }
    float4 bias = *(const float4*)(in_b + n0 + tx * 4);
    float bv[4] = {bias.x, bias.y, bias.z, bias.w};
    #pragma unroll
    for (int i = 0; i < 4; ++i) {
        int m = bm * 64 + ty * 4 + i;
        float4 o;
        o.x = acc[i][0] + bv[0];
        o.y = acc[i][1] + bv[1];
        o.z = acc[i][2] + bv[2];
        o.w = acc[i][3] + bv[3];
        *(float4*)(xproj + (size_t)m * CC + n0 + tx * 4) = o;
    }
}

// ---------------- K4: deformable bilinear sampling ----------------
// grid: NPIX blocks, 256 threads (thread = channel)
__global__ __launch_bounds__(256) void k4_sample(const float* __restrict__ xproj,
        const float* __restrict__ offmask, float* __restrict__ accb) {
    int n = blockIdx.x;
    int x = n & 63, y = (n >> 6) & 63, b = n >> 12;
    int t = threadIdx.x;
    __shared__ int   s_idx[9][4];
    __shared__ float s_w[9][4];
    if (t < 9) {
        int k = t;
        float dx = offmask[(size_t)n * 32 + 2 * k];
        float dy = offmask[(size_t)n * 32 + 2 * k + 1];
        float m  = offmask[(size_t)n * 32 + 18 + k];
        float py = (float)y + (float)(k / 3 - 1) + dy;
        float px = (float)x + (float)(k % 3 - 1) + dx;
        float y0f = floorf(py), x0f = floorf(px);
        float wy = py - y0f, wx = px - x0f;
        int y0 = (int)y0f, x0 = (int)x0f;
        int y1 = y0 + 1, x1 = x0 + 1;
        float vy0 = (y0 >= 0 && y0 < HH) ? 1.f : 0.f;
        float vy1 = (y1 >= 0 && y1 < HH) ? 1.f : 0.f;
        float vx0 = (x0 >= 0 && x0 < WW) ? 1.f : 0.f;
        float vx1 = (x1 >= 0 && x1 < WW) ? 1.f : 0.f;
        int yc0 = max(0, min(HH - 1, y0)), yc1 = max(0, min(HH - 1, y1));
        int xc0 = max(0, min(WW - 1, x0)), xc1 = max(0, min(WW - 1, x1));
        int base = b * HH * WW;
        s_idx[k][0] = (base + yc0 * WW + xc0) * CC;
        s_idx[k][1] = (base + yc0 * WW + xc1) * CC;
        s_idx[k][2] = (base + yc1 * WW + xc0) * CC;
        s_idx[k][3] = (base + yc1 * WW + xc1) * CC;
        s_w[k][0] = m * (1.f - wy) * (1.f - wx) * vy0 * vx0;
        s_w[k][1] = m * (1.f - wy) * wx * vy0 * vx1;
        s_w[k][2] = m * wy * (1.f - wx) * vy1 * vx0;
        s_w[k][3] = m * wy * wx * vy1 * vx1;
    }
    __syncthreads();
    int c = t;
    float a = 0.f;
    #pragma unroll
    for (int k = 0; k < 9; ++k) {
        a += s_w[k][0] * xproj[s_idx[k][0] + c]
           + s_w[k][1] * xproj[s_idx[k][1] + c]
           + s_w[k][2] * xproj[s_idx[k][2] + c]
           + s_w[k][3] * xproj[s_idx[k][3] + c];
    }
    accb[(size_t)n * CC + c] = a;
}

// ---------------- K5: y = acc @ out_w + out_b -> BN -> ReLU -> +x1, NCHW out ----------------
// grid: 512*4 = 2048 blocks, 256 threads
__global__ __launch_bounds__(256) void k5_outproj(const float* __restrict__ accb,
        const float* __restrict__ out_w, const float* __restrict__ out_b,
        const float* __restrict__ bn_g, const float* __restrict__ bn_b,
        const float* __restrict__ bn_mean, const float* __restrict__ bn_var,
        const float* __restrict__ x1, float* __restrict__ out) {
    int bn = blockIdx.x & 3;
    int bm = blockIdx.x >> 2;
    int n0 = bn * 64;
    int y = bm & 63, b = bm >> 6;
    __shared__ float smem[32 * 68 + 32 * 64];   // As[32][68] | Bs[32][64]; reused as Lo[64][65]
    float* As = smem;
    float* Bs = smem + 32 * 68;
    int t = threadIdx.x;
    int tx = t & 15, ty = t >> 4;
    float acc[4][4] = {};

    for (int k0 = 0; k0 < CC; k0 += 32) {
        #pragma unroll
        for (int i = 0; i < 8; ++i) {
            int idx = t + i * 256;
            int mm = idx >> 5, kk = idx & 31;
            As[kk * 68 + mm] = accb[(size_t)(bm * 64 + mm) * CC + k0 + kk];
        }
        #pragma unroll
        for (int i = 0; i < 8; ++i) {
            int idx = t + i * 256;
            int k = idx >> 6, nn = idx & 63;
            Bs[k * 64 + nn] = out_w[(size_t)(k0 + k) * CC + n0 + nn];
        }
        __syncthreads();
        #pragma unroll
        for (int kk = 0; kk < 32; ++kk) {
            float4 a4 = *(const float4*)(As + kk * 68 + ty * 4);
            float4 b4 = *(const float4*)(Bs + kk * 64 + tx * 4);
            float av[4] = {a4.x, a4.y, a4.z, a4.w};
            float bv[4] = {b4.x, b4.y, b4.z, b4.w};
            #pragma unroll
            for (int i = 0; i < 4; ++i)
                #pragma unroll
                for (int j = 0; j < 4; ++j)
                    acc[i][j] = fmaf(av[i], bv[j], acc[i][j]);
        }
        __syncthreads();
    }
    // bounce via LDS for coalesced NCHW store; fuse bias+BN+ReLU+residual
    float* Lo = smem;   // [64][65]: Lo[m][co]
    #pragma unroll
    for (int i = 0; i < 4; ++i)
        #pragma unroll
        for (int j = 0; j < 4; ++j)
            Lo[(ty * 4 + i) * 65 + tx * 4 + j] = acc[i][j];
    __syncthreads();
    #pragma unroll
    for (int it = 0; it < 16; ++it) {
        int idx = t + it * 256;
        int xx = idx & 63;
        int cw = idx >> 6;            // 0..63
        int co = n0 + cw;
        float val = Lo[xx * 65 + cw] + out_b[co];
        float scale = bn_g[co] * rsqrtf(bn_var[co] + EPSV);
        float shift = bn_b[co] - bn_mean[co] * scale;
        val = fmaxf(val * scale + shift, 0.f);
        size_t g = (size_t)((b * CC + co) * HH + y) * WW + xx;
        out[g] = val + x1[g];
    }
}

extern "C" void kernel_launch(void* const* d_in, const int* in_sizes, int n_in,
                              void* d_out, int out_size, void* d_ws, size_t ws_size,
                              hipStream_t stream) {
    const float* x1     = (const float*)d_in[0];
    const float* x2     = (const float*)d_in[1];
    const float* dw_w   = (const float*)d_in[2];
    const float* dw_b   = (const float*)d_in[3];
    const float* ln_g   = (const float*)d_in[4];
    const float* ln_b   = (const float*)d_in[5];
    const float* off_w  = (const float*)d_in[6];
    const float* off_b  = (const float*)d_in[7];
    const float* mask_w = (const float*)d_in[8];
    const float* mask_b = (const float*)d_in[9];
    const float* in_w   = (const float*)d_in[10];
    const float* in_b   = (const float*)d_in[11];
    const float* out_w  = (const float*)d_in[12];
    const float* out_b  = (const float*)d_in[13];
    const float* bn_g   = (const float*)d_in[14];
    const float* bn_b   = (const float*)d_in[15];
    const float* bn_mean= (const float*)d_in[16];
    const float* bn_var = (const float*)d_in[17];
    float* out = (float*)d_out;

    float* ws      = (float*)d_ws;
    float* guide   = ws;                          // slot1: NPIX*C floats (33.5 MB)
    float* slot2   = ws + (size_t)NPIX * CC;      // slot2: NPIX*C floats (feat, then xproj)
    float* offmask = ws + (size_t)2 * NPIX * CC;  // slot3: NPIX*32 floats (4 MB)
    float* feat    = slot2;                       // K2a out, K2b in (dead after K2b)
    float* xproj   = slot2;                       // K3 out (overwrites feat)
    float* accb    = guide;                       // guide dead after K2a -> alias

    hipLaunchKernelGGL(k1_guide,   dim3(2048), dim3(256), 0, stream, x2, guide);
    hipLaunchKernelGGL(k2a_feat,   dim3(NPIX), dim3(256), 0, stream, guide, dw_w, dw_b,
                       ln_g, ln_b, feat);
    hipLaunchKernelGGL(k2b_heads,  dim3(512),  dim3(256), 0, stream, feat, off_w, off_b,
                       mask_w, mask_b, offmask);
    hipLaunchKernelGGL(k3_inproj,  dim3(2048), dim3(256), 0, stream, x1, in_w, in_b, xproj);
    hipLaunchKernelGGL(k4_sample,  dim3(NPIX), dim3(256), 0, stream, xproj, offmask, accb);
    hipLaunchKernelGGL(k5_outproj, dim3(2048), dim3(256), 0, stream, accb, out_w, out_b,
                       bn_g, bn_b, bn_mean, bn_var, x1, out);
}

// Round 3
// 257.230 us; speedup vs baseline: 1.7695x; 1.1394x over previous
//
#include <hip/hip_runtime.h>
#include <math.h>

#define BB 8
#define CC 256
#define HH 64
#define WW 64
#define H2 32
#define W2 32
#define NPIX (BB*HH*WW)
#define EPSV 1e-5f

typedef unsigned short ushortT;
using short8  = __attribute__((ext_vector_type(8))) short;
using floatx4 = __attribute__((ext_vector_type(4))) float;

__device__ inline float b2f(ushortT u) {
    unsigned int x = ((unsigned int)u) << 16;
    float f; __builtin_memcpy(&f, &x, 4); return f;
}
__device__ inline ushortT f2b(float f) {
    unsigned int x; __builtin_memcpy(&x, &f, 4);
    unsigned int r = x + 0x7fffu + ((x >> 16) & 1u);   // RNE
    return (ushortT)(r >> 16);
}

// ---------------- K0: transpose+convert weights: in_w/out_w [k][n] f32 -> BT [n][k] bf16 ----------
// grid: 32 blocks (16 tiles x 2 matrices), 256 threads
__global__ __launch_bounds__(256) void k0_prep(const float* __restrict__ in_w,
        const float* __restrict__ out_w, ushortT* __restrict__ BTin,
        ushortT* __restrict__ BTout) {
    int blk = blockIdx.x;
    const float* W = (blk < 16) ? in_w : out_w;
    ushortT* D = (blk < 16) ? BTin : BTout;
    int tid = blk & 15;
    int k0 = (tid >> 2) * 64, n0 = (tid & 3) * 64;
    __shared__ ushortT tl[64][72];
    int t = threadIdx.x;
    #pragma unroll
    for (int i = 0; i < 4; ++i) {
        int e = t + i * 256;           // 0..1023 float4 slots
        int r = e >> 4;                // k row
        int cg = (e & 15) * 4;         // n col group
        float4 v = *(const float4*)(W + (size_t)(k0 + r) * CC + n0 + cg);
        tl[cg + 0][r] = f2b(v.x); tl[cg + 1][r] = f2b(v.y);
        tl[cg + 2][r] = f2b(v.z); tl[cg + 3][r] = f2b(v.w);
    }
    __syncthreads();
    #pragma unroll
    for (int i = 0; i < 2; ++i) {
        int e = t + i * 256;           // 0..511 chunks of 8
        int n = e >> 3, kg = (e & 7) * 8;
        *(short8*)(D + (size_t)(n0 + n) * CC + k0 + kg) = *(const short8*)(&tl[n][kg]);
    }
}

// ---------------- K1: bilinear 2x upsample of x2, |x21-x22| -> guide NHWC bf16 ----------------
__global__ __launch_bounds__(256) void k1_guide(const float* __restrict__ x2,
                                                ushortT* __restrict__ guide) {
    int blk = blockIdx.x;
    int c0 = (blk & 3) * 64;
    int y  = (blk >> 2) & 63;
    int b  = blk >> 8;
    int bb = b & 3;
    __shared__ float tile[64][65];
    int t = threadIdx.x;
    int x = t & 63;

    float sx = 0.5f * x - 0.25f;
    float sy = 0.5f * y - 0.25f;
    float fx0 = floorf(sx), fy0 = floorf(sy);
    float wx = sx - fx0, wy = sy - fy0;
    int jx0 = (int)fx0, jy0 = (int)fy0;
    int ix0 = max(0, min(W2 - 1, jx0));
    int ix1 = max(0, min(W2 - 1, jx0 + 1));
    int iy0 = max(0, min(H2 - 1, jy0));
    int iy1 = max(0, min(H2 - 1, jy0 + 1));
    float w00 = (1.f - wy) * (1.f - wx), w01 = (1.f - wy) * wx;
    float w10 = wy * (1.f - wx), w11 = wy * wx;
    int o00 = iy0 * W2 + ix0, o01 = iy0 * W2 + ix1;
    int o10 = iy1 * W2 + ix0, o11 = iy1 * W2 + ix1;

    int cl = t >> 6;
    #pragma unroll
    for (int it = 0; it < 16; ++it) {
        int c = cl + it * 4;
        const float* p1 = x2 + (size_t)((bb * CC + c0 + c) * H2) * W2;
        const float* p2 = x2 + (size_t)(((bb + 4) * CC + c0 + c) * H2) * W2;
        float v1 = w00 * p1[o00] + w01 * p1[o01] + w10 * p1[o10] + w11 * p1[o11];
        float v2 = w00 * p2[o00] + w01 * p2[o01] + w10 * p2[o10] + w11 * p2[o11];
        tile[c][x] = fabsf(v1 - v2);
    }
    __syncthreads();
    #pragma unroll
    for (int it = 0; it < 16; ++it) {
        int idx = t + it * 256;
        int cw = idx & 63;
        int xw = idx >> 6;
        guide[(size_t)((b * HH + y) * WW + xw) * CC + c0 + cw] = f2b(tile[cw][xw]);
    }
}

// ---------------- K1t: transpose x1 NCHW f32 -> x1t NHWC bf16 ----------------
__global__ __launch_bounds__(256) void k1t_x1(const float* __restrict__ x1,
                                              ushortT* __restrict__ x1t) {
    int blk = blockIdx.x;
    int c0 = (blk & 3) * 64;
    int y  = (blk >> 2) & 63;
    int b  = blk >> 8;
    __shared__ ushortT tile[64][65];
    int t = threadIdx.x;
    int x = t & 63;
    int cl = t >> 6;
    #pragma unroll
    for (int it = 0; it < 16; ++it) {
        int c = cl + it * 4;
        tile[c][x] = f2b(x1[(size_t)((b * CC + c0 + c) * HH + y) * WW + x]);
    }
    __syncthreads();
    #pragma unroll
    for (int it = 0; it < 16; ++it) {
        int idx = t + it * 256;
        int cw = idx & 63;
        int xw = idx >> 6;
        x1t[(size_t)((b * HH + y) * WW + xw) * CC + c0 + cw] = tile[cw][xw];
    }
}

// ---------------- K2a: dwconv3x3 + LN + GELU -> feat NHWC bf16 ----------------
// grid: NPIX blocks (XCD-swizzled), 256 threads (thread = channel)
__global__ __launch_bounds__(256) void k2a_feat(const ushortT* __restrict__ guide,
        const float* __restrict__ dw_w, const float* __restrict__ dw_b,
        const float* __restrict__ ln_g, const float* __restrict__ ln_b,
        ushortT* __restrict__ feat) {
    int n = ((blockIdx.x & 7) << 12) | (blockIdx.x >> 3);   // XCD-chunked bijection
    int x = n & 63, y = (n >> 6) & 63, b = n >> 12;
    int c = threadIdx.x;

    float v = dw_b[c];
    #pragma unroll
    for (int dy = -1; dy <= 1; ++dy) {
        #pragma unroll
        for (int dx = -1; dx <= 1; ++dx) {
            int yy = y + dy, xx = x + dx;
            if (yy >= 0 && yy < HH && xx >= 0 && xx < WW) {
                v += b2f(guide[(size_t)((b * HH + yy) * WW + xx) * CC + c])
                   * dw_w[((dy + 1) * 3 + (dx + 1)) * CC + c];
            }
        }
    }
    float s1 = v, s2 = v * v;
    #pragma unroll
    for (int off = 32; off; off >>= 1) {
        s1 += __shfl_xor(s1, off);
        s2 += __shfl_xor(s2, off);
    }
    __shared__ float red[8];
    int wid = c >> 6, lane = c & 63;
    if (lane == 0) { red[wid] = s1; red[wid + 4] = s2; }
    __syncthreads();
    float t1 = red[0] + red[1] + red[2] + red[3];
    float t2 = red[4] + red[5] + red[6] + red[7];
    float mean = t1 * (1.0f / CC);
    float var  = t2 * (1.0f / CC) - mean * mean;
    v = (v - mean) * rsqrtf(var + EPSV) * ln_g[c] + ln_b[c];
    float u2 = 1.5957691216057308f * (v + 0.044715f * v * v * v);
    v = v * __frcp_rn(1.0f + __expf(-u2));
    feat[(size_t)n * CC + c] = f2b(v);
}

// ---------------- K2b: offmask = feat @ [off_w|mask_w] + bias, softmax(mask) ----------------
__global__ __launch_bounds__(256) void k2b_heads(const ushortT* __restrict__ feat,
        const float* __restrict__ off_w, const float* __restrict__ off_b,
        const float* __restrict__ mask_w, const float* __restrict__ mask_b,
        float* __restrict__ offmask) {
    int p0 = blockIdx.x * 64;
    int t = threadIdx.x;
    __shared__ float Wc[CC * 32];
    __shared__ float As[64 * 36];

    for (int idx = t; idx < CC * 32; idx += 256) {
        int k = idx >> 5, j = idx & 31;
        float w = 0.f;
        if (j < 18)      w = off_w[k * 18 + j];
        else if (j < 27) w = mask_w[k * 9 + (j - 18)];
        Wc[idx] = w;
    }

    int tx = t & 7, ty = t >> 3;
    int n0 = tx * 4, m0 = ty * 2;
    float acc[2][4] = {};

    for (int k0 = 0; k0 < CC; k0 += 32) {
        {
            int m = t >> 2, kq = (t & 3) * 8;
            short8 v = *(const short8*)(feat + (size_t)(p0 + m) * CC + k0 + kq);
            #pragma unroll
            for (int j = 0; j < 8; ++j)
                As[m * 36 + kq + j] = b2f((ushortT)v[j]);
        }
        __syncthreads();
        #pragma unroll
        for (int kk = 0; kk < 32; ++kk) {
            float a0 = As[m0 * 36 + kk];
            float a1 = As[(m0 + 1) * 36 + kk];
            const float* bp = Wc + (k0 + kk) * 32 + n0;
            #pragma unroll
            for (int ni = 0; ni < 4; ++ni) {
                float bw = bp[ni];
                acc[0][ni] = fmaf(a0, bw, acc[0][ni]);
                acc[1][ni] = fmaf(a1, bw, acc[1][ni]);
            }
        }
        __syncthreads();
    }

    float* O = As;
    #pragma unroll
    for (int ni = 0; ni < 4; ++ni) {
        int j = n0 + ni;
        float bias = (j < 18) ? off_b[j] : ((j < 27) ? mask_b[j - 18] : 0.f);
        O[m0 * 36 + j] = acc[0][ni] + bias;
        O[(m0 + 1) * 36 + j] = acc[1][ni] + bias;
    }
    __syncthreads();
    if (t < 64) {
        float* row = O + t * 36 + 18;
        float mx = row[0];
        #pragma unroll
        for (int k = 1; k < 9; ++k) mx = fmaxf(mx, row[k]);
        float e9[9], ssum = 0.f;
        #pragma unroll
        for (int k = 0; k < 9; ++k) { e9[k] = __expf(row[k] - mx); ssum += e9[k]; }
        float inv = __frcp_rn(ssum);
        #pragma unroll
        for (int k = 0; k < 9; ++k) row[k] = e9[k] * inv;
    }
    __syncthreads();
    #pragma unroll
    for (int i = 0; i < 8; ++i) {
        int idx = t + i * 256;
        int p = idx >> 5, j = idx & 31;
        offmask[(size_t)(p0 + p) * 32 + j] = O[p * 36 + j];
    }
}

// ---------------- K3: xproj(bf16) = x1t(bf16) @ BTin^T + in_b  [MFMA] ----------------
// grid: 256 Mtiles x 2 Ntiles = 512 blocks, 256 threads = 4 waves (2x2), tile 128x128, BK=32
__global__ __launch_bounds__(256) void k3_mfma(const ushortT* __restrict__ A,
        const ushortT* __restrict__ Bt, const float* __restrict__ bias,
        ushortT* __restrict__ C) {
    __shared__ short Asb[128 * 40];
    __shared__ short Bsb[128 * 40];
    int t = threadIdx.x;
    int m0 = (blockIdx.x >> 1) * 128;
    int n0 = (blockIdx.x & 1) * 128;
    int lane = t & 63, w = t >> 6;
    int wr = w >> 1, wc = w & 1;
    int cl = lane & 15, rg = lane >> 4;

    floatx4 acc[4][4];
    floatx4 zero = {0.f, 0.f, 0.f, 0.f};
    #pragma unroll
    for (int i = 0; i < 4; ++i)
        #pragma unroll
        for (int j = 0; j < 4; ++j) acc[i][j] = zero;

    for (int k0 = 0; k0 < CC; k0 += 32) {
        #pragma unroll
        for (int i = 0; i < 2; ++i) {
            int cidx = t + i * 256;
            int row = cidx >> 2, q = cidx & 3;
            *(short8*)(&Asb[row * 40 + q * 8]) =
                *(const short8*)(A + (size_t)(m0 + row) * CC + k0 + q * 8);
            *(short8*)(&Bsb[row * 40 + q * 8]) =
                *(const short8*)(Bt + (size_t)(n0 + row) * CC + k0 + q * 8);
        }
        __syncthreads();
        short8 af[4], bfr[4];
        #pragma unroll
        for (int f = 0; f < 4; ++f) {
            af[f]  = *(const short8*)(&Asb[(wr * 64 + f * 16 + cl) * 40 + rg * 8]);
            bfr[f] = *(const short8*)(&Bsb[(wc * 64 + f * 16 + cl) * 40 + rg * 8]);
        }
        #pragma unroll
        for (int fr = 0; fr < 4; ++fr)
            #pragma unroll
            for (int fc = 0; fc < 4; ++fc)
                acc[fr][fc] = __builtin_amdgcn_mfma_f32_16x16x32_bf16(
                    af[fr], bfr[fc], acc[fr][fc], 0, 0, 0);
        __syncthreads();
    }
    #pragma unroll
    for (int fc = 0; fc < 4; ++fc) {
        int n = n0 + wc * 64 + fc * 16 + cl;
        float bv = bias[n];
        #pragma unroll
        for (int fr = 0; fr < 4; ++fr) {
            int mr = m0 + wr * 64 + fr * 16 + rg * 4;
            #pragma unroll
            for (int j = 0; j < 4; ++j)
                C[(size_t)(mr + j) * CC + n] = f2b(acc[fr][fc][j] + bv);
        }
    }
}

// ---------------- K4: deformable bilinear sampling (bf16 in/out) ----------------
// grid: NPIX blocks (XCD-swizzled), 256 threads (thread = channel)
__global__ __launch_bounds__(256) void k4_sample(const ushortT* __restrict__ xproj,
        const float* __restrict__ offmask, ushortT* __restrict__ accb) {
    int n = ((blockIdx.x & 7) << 12) | (blockIdx.x >> 3);   // XCD-chunked bijection
    int x = n & 63, y = (n >> 6) & 63, b = n >> 12;
    int t = threadIdx.x;
    __shared__ int   s_idx[9][4];
    __shared__ float s_w[9][4];
    if (t < 9) {
        int k = t;
        float dx = offmask[(size_t)n * 32 + 2 * k];
        float dy = offmask[(size_t)n * 32 + 2 * k + 1];
        float m  = offmask[(size_t)n * 32 + 18 + k];
        float py = (float)y + (float)(k / 3 - 1) + dy;
        float px = (float)x + (float)(k % 3 - 1) + dx;
        float y0f = floorf(py), x0f = floorf(px);
        float wy = py - y0f, wx = px - x0f;
        int y0 = (int)y0f, x0 = (int)x0f;
        int y1 = y0 + 1, x1 = x0 + 1;
        float vy0 = (y0 >= 0 && y0 < HH) ? 1.f : 0.f;
        float vy1 = (y1 >= 0 && y1 < HH) ? 1.f : 0.f;
        float vx0 = (x0 >= 0 && x0 < WW) ? 1.f : 0.f;
        float vx1 = (x1 >= 0 && x1 < WW) ? 1.f : 0.f;
        int yc0 = max(0, min(HH - 1, y0)), yc1 = max(0, min(HH - 1, y1));
        int xc0 = max(0, min(WW - 1, x0)), xc1 = max(0, min(WW - 1, x1));
        int base = b * HH * WW;
        s_idx[k][0] = (base + yc0 * WW + xc0) * CC;
        s_idx[k][1] = (base + yc0 * WW + xc1) * CC;
        s_idx[k][2] = (base + yc1 * WW + xc0) * CC;
        s_idx[k][3] = (base + yc1 * WW + xc1) * CC;
        s_w[k][0] = m * (1.f - wy) * (1.f - wx) * vy0 * vx0;
        s_w[k][1] = m * (1.f - wy) * wx * vy0 * vx1;
        s_w[k][2] = m * wy * (1.f - wx) * vy1 * vx0;
        s_w[k][3] = m * wy * wx * vy1 * vx1;
    }
    __syncthreads();
    int c = t;
    float a = 0.f;
    #pragma unroll
    for (int k = 0; k < 9; ++k) {
        a += s_w[k][0] * b2f(xproj[s_idx[k][0] + c])
           + s_w[k][1] * b2f(xproj[s_idx[k][1] + c])
           + s_w[k][2] * b2f(xproj[s_idx[k][2] + c])
           + s_w[k][3] * b2f(xproj[s_idx[k][3] + c]);
    }
    accb[(size_t)n * CC + c] = f2b(a);
}

// ---------------- K5: out = relu(bn(accb @ BTout^T + out_b)) + x1, NCHW  [MFMA] ----------------
// grid: 512 blocks, 256 threads, tile 128x128
__global__ __launch_bounds__(256) void k5_mfma(const ushortT* __restrict__ A,
        const ushortT* __restrict__ Bt, const float* __restrict__ out_b,
        const float* __restrict__ bn_g, const float* __restrict__ bn_b,
        const float* __restrict__ bn_mean, const float* __restrict__ bn_var,
        const float* __restrict__ x1, float* __restrict__ out) {
    __shared__ __align__(16) char smem[20480];
    short* Asb = (short*)smem;
    short* Bsb = (short*)(smem + 10240);
    float* Lo  = (float*)smem;            // epilogue reuse: [128][33] f32 = 16896B
    int t = threadIdx.x;
    int m0 = (blockIdx.x >> 1) * 128;
    int n0 = (blockIdx.x & 1) * 128;
    int lane = t & 63, w = t >> 6;
    int wr = w >> 1, wc = w & 1;
    int cl = lane & 15, rg = lane >> 4;

    floatx4 acc[4][4];
    floatx4 zero = {0.f, 0.f, 0.f, 0.f};
    #pragma unroll
    for (int i = 0; i < 4; ++i)
        #pragma unroll
        for (int j = 0; j < 4; ++j) acc[i][j] = zero;

    for (int k0 = 0; k0 < CC; k0 += 32) {
        #pragma unroll
        for (int i = 0; i < 2; ++i) {
            int cidx = t + i * 256;
            int row = cidx >> 2, q = cidx & 3;
            *(short8*)(&Asb[row * 40 + q * 8]) =
                *(const short8*)(A + (size_t)(m0 + row) * CC + k0 + q * 8);
            *(short8*)(&Bsb[row * 40 + q * 8]) =
                *(const short8*)(Bt + (size_t)(n0 + row) * CC + k0 + q * 8);
        }
        __syncthreads();
        short8 af[4], bfr[4];
        #pragma unroll
        for (int f = 0; f < 4; ++f) {
            af[f]  = *(const short8*)(&Asb[(wr * 64 + f * 16 + cl) * 40 + rg * 8]);
            bfr[f] = *(const short8*)(&Bsb[(wc * 64 + f * 16 + cl) * 40 + rg * 8]);
        }
        #pragma unroll
        for (int fr = 0; fr < 4; ++fr)
            #pragma unroll
            for (int fc = 0; fc < 4; ++fc)
                acc[fr][fc] = __builtin_amdgcn_mfma_f32_16x16x32_bf16(
                    af[fr], bfr[fc], acc[fr][fc], 0, 0, 0);
        __syncthreads();
    }

    // epilogue: 4 phases of 32 cols each; LDS bounce -> coalesced NCHW stores
    int b = m0 >> 12;
    int y0 = (m0 >> 6) & 63;
    #pragma unroll
    for (int ph = 0; ph < 4; ++ph) {
        if (wc == (ph >> 1)) {
            #pragma unroll
            for (int fc2 = 0; fc2 < 2; ++fc2) {
                int fc = (ph & 1) * 2 + fc2;
                int cw = fc2 * 16 + cl;
                #pragma unroll
                for (int fr = 0; fr < 4; ++fr) {
                    int mr = wr * 64 + fr * 16 + rg * 4;
                    #pragma unroll
                    for (int j = 0; j < 4; ++j)
                        Lo[(mr + j) * 33 + cw] = acc[fr][fc][j];
                }
            }
        }
        __syncthreads();
        #pragma unroll
        for (int i = 0; i < 16; ++i) {
            int e = t + i * 256;                   // 0..4095
            int x = e & 63, ry = (e >> 6) & 1, cw = e >> 7;
            int co = n0 + ph * 32 + cw;
            float val = Lo[(ry * 64 + x) * 33 + cw] + out_b[co];
            float scale = bn_g[co] * rsqrtf(bn_var[co] + EPSV);
            float sh = bn_b[co] - bn_mean[co] * scale;
            val = fmaxf(val * scale + sh, 0.f);
            size_t g = (size_t)((b * CC + co) * HH + y0 + ry) * WW + x;
            out[g] = val + x1[g];
        }
        __syncthreads();
    }
}

extern "C" void kernel_launch(void* const* d_in, const int* in_sizes, int n_in,
                              void* d_out, int out_size, void* d_ws, size_t ws_size,
                              hipStream_t stream) {
    const float* x1     = (const float*)d_in[0];
    const float* x2     = (const float*)d_in[1];
    const float* dw_w   = (const float*)d_in[2];
    const float* dw_b   = (const float*)d_in[3];
    const float* ln_g   = (const float*)d_in[4];
    const float* ln_b   = (const float*)d_in[5];
    const float* off_w  = (const float*)d_in[6];
    const float* off_b  = (const float*)d_in[7];
    const float* mask_w = (const float*)d_in[8];
    const float* mask_b = (const float*)d_in[9];
    const float* in_w   = (const float*)d_in[10];
    const float* in_b   = (const float*)d_in[11];
    const float* out_w  = (const float*)d_in[12];
    const float* out_b  = (const float*)d_in[13];
    const float* bn_g   = (const float*)d_in[14];
    const float* bn_b   = (const float*)d_in[15];
    const float* bn_mean= (const float*)d_in[16];
    const float* bn_var = (const float*)d_in[17];
    float* out = (float*)d_out;

    char* wsb = (char*)d_ws;
    const size_t SZ = (size_t)NPIX * CC * 2;        // 16.78 MB per bf16 tensor
    ushortT* guide   = (ushortT*)wsb;               // slot0
    ushortT* feat    = (ushortT*)(wsb + SZ);        // slot1
    ushortT* x1t     = (ushortT*)(wsb + 2 * SZ);    // slot2
    float*   offmask = (float*)(wsb + 3 * SZ);      // 4.19 MB
    ushortT* BTin    = (ushortT*)(wsb + 3 * SZ + (size_t)NPIX * 32 * 4);
    ushortT* BTout   = BTin + CC * CC;
    ushortT* xproj   = guide;                       // guide dead after k2a
    ushortT* accb    = feat;                        // feat dead after k2b

    hipLaunchKernelGGL(k0_prep,   dim3(32),   dim3(256), 0, stream, in_w, out_w, BTin, BTout);
    hipLaunchKernelGGL(k1_guide,  dim3(2048), dim3(256), 0, stream, x2, guide);
    hipLaunchKernelGGL(k1t_x1,    dim3(2048), dim3(256), 0, stream, x1, x1t);
    hipLaunchKernelGGL(k2a_feat,  dim3(NPIX), dim3(256), 0, stream, guide, dw_w, dw_b,
                       ln_g, ln_b, feat);
    hipLaunchKernelGGL(k2b_heads, dim3(512),  dim3(256), 0, stream, feat, off_w, off_b,
                       mask_w, mask_b, offmask);
    hipLaunchKernelGGL(k3_mfma,   dim3(512),  dim3(256), 0, stream, x1t, BTin, in_b, xproj);
    hipLaunchKernelGGL(k4_sample, dim3(NPIX), dim3(256), 0, stream, xproj, offmask, accb);
    hipLaunchKernelGGL(k5_mfma,   dim3(512),  dim3(256), 0, stream, accb, BTout, out_b,
                       bn_g, bn_b, bn_mean, bn_var, x1, out);
}

// Round 4
// 157.116 us; speedup vs baseline: 2.8970x; 1.6372x over previous
//
#include <hip/hip_runtime.h>
#include <math.h>

#define BB 8
#define CC 256
#define HH 64
#define WW 64
#define H2 32
#define W2 32
#define NPIX (BB*HH*WW)
#define EPSV 1e-5f

typedef unsigned short ushortT;
using short8  = __attribute__((ext_vector_type(8))) short;
using floatx4 = __attribute__((ext_vector_type(4))) float;

__device__ inline float b2f(ushortT u) {
    unsigned int x = ((unsigned int)u) << 16;
    float f; __builtin_memcpy(&f, &x, 4); return f;
}
__device__ inline ushortT f2b(float f) {
    unsigned int x; __builtin_memcpy(&x, &f, 4);
    unsigned int r = x + 0x7fffu + ((x >> 16) & 1u);   // RNE
    return (ushortT)(r >> 16);
}

// ---------------- K0: transpose+convert weights: in_w/out_w [k][n] f32 -> BT [n][k] bf16 ----------
__global__ __launch_bounds__(256) void k0_prep(const float* __restrict__ in_w,
        const float* __restrict__ out_w, ushortT* __restrict__ BTin,
        ushortT* __restrict__ BTout) {
    int blk = blockIdx.x;
    const float* W = (blk < 16) ? in_w : out_w;
    ushortT* D = (blk < 16) ? BTin : BTout;
    int tid = blk & 15;
    int k0 = (tid >> 2) * 64, n0 = (tid & 3) * 64;
    __shared__ ushortT tl[64][72];
    int t = threadIdx.x;
    #pragma unroll
    for (int i = 0; i < 4; ++i) {
        int e = t + i * 256;
        int r = e >> 4;
        int cg = (e & 15) * 4;
        float4 v = *(const float4*)(W + (size_t)(k0 + r) * CC + n0 + cg);
        tl[cg + 0][r] = f2b(v.x); tl[cg + 1][r] = f2b(v.y);
        tl[cg + 2][r] = f2b(v.z); tl[cg + 3][r] = f2b(v.w);
    }
    __syncthreads();
    #pragma unroll
    for (int i = 0; i < 2; ++i) {
        int e = t + i * 256;
        int n = e >> 3, kg = (e & 7) * 8;
        *(short8*)(D + (size_t)(n0 + n) * CC + k0 + kg) = *(const short8*)(&tl[n][kg]);
    }
}

// ---------------- K1: bilinear 2x upsample of x2, |x21-x22| -> guide NHWC bf16 ----------------
__global__ __launch_bounds__(256) void k1_guide(const float* __restrict__ x2,
                                                ushortT* __restrict__ guide) {
    int blk = blockIdx.x;
    int c0 = (blk & 3) * 64;
    int y  = (blk >> 2) & 63;
    int b  = blk >> 8;
    int bb = b & 3;
    __shared__ float tile[64][65];
    int t = threadIdx.x;
    int x = t & 63;

    float sx = 0.5f * x - 0.25f;
    float sy = 0.5f * y - 0.25f;
    float fx0 = floorf(sx), fy0 = floorf(sy);
    float wx = sx - fx0, wy = sy - fy0;
    int jx0 = (int)fx0, jy0 = (int)fy0;
    int ix0 = max(0, min(W2 - 1, jx0));
    int ix1 = max(0, min(W2 - 1, jx0 + 1));
    int iy0 = max(0, min(H2 - 1, jy0));
    int iy1 = max(0, min(H2 - 1, jy0 + 1));
    float w00 = (1.f - wy) * (1.f - wx), w01 = (1.f - wy) * wx;
    float w10 = wy * (1.f - wx), w11 = wy * wx;
    int o00 = iy0 * W2 + ix0, o01 = iy0 * W2 + ix1;
    int o10 = iy1 * W2 + ix0, o11 = iy1 * W2 + ix1;

    int cl = t >> 6;
    #pragma unroll
    for (int it = 0; it < 16; ++it) {
        int c = cl + it * 4;
        const float* p1 = x2 + (size_t)((bb * CC + c0 + c) * H2) * W2;
        const float* p2 = x2 + (size_t)(((bb + 4) * CC + c0 + c) * H2) * W2;
        float v1 = w00 * p1[o00] + w01 * p1[o01] + w10 * p1[o10] + w11 * p1[o11];
        float v2 = w00 * p2[o00] + w01 * p2[o01] + w10 * p2[o10] + w11 * p2[o11];
        tile[c][x] = fabsf(v1 - v2);
    }
    __syncthreads();
    #pragma unroll
    for (int it = 0; it < 16; ++it) {
        int idx = t + it * 256;
        int cw = idx & 63;
        int xw = idx >> 6;
        guide[(size_t)((b * HH + y) * WW + xw) * CC + c0 + cw] = f2b(tile[cw][xw]);
    }
}

// ---------------- K1t: transpose x1 NCHW f32 -> x1t NHWC bf16 ----------------
__global__ __launch_bounds__(256) void k1t_x1(const float* __restrict__ x1,
                                              ushortT* __restrict__ x1t) {
    int blk = blockIdx.x;
    int c0 = (blk & 3) * 64;
    int y  = (blk >> 2) & 63;
    int b  = blk >> 8;
    __shared__ ushortT tile[64][65];
    int t = threadIdx.x;
    int x = t & 63;
    int cl = t >> 6;
    #pragma unroll
    for (int it = 0; it < 16; ++it) {
        int c = cl + it * 4;
        tile[c][x] = f2b(x1[(size_t)((b * CC + c0 + c) * HH + y) * WW + x]);
    }
    __syncthreads();
    #pragma unroll
    for (int it = 0; it < 16; ++it) {
        int idx = t + it * 256;
        int cw = idx & 63;
        int xw = idx >> 6;
        x1t[(size_t)((b * HH + y) * WW + xw) * CC + c0 + cw] = tile[cw][xw];
    }
}

// ---------------- K2a: dwconv3x3 + LN + GELU -> feat NHWC bf16 ----------------
// grid: NPIX/8 = 4096 blocks (XCD-swizzled), 256 threads: px = t>>5 (8 px), cg = t&31 (8 ch each)
__global__ __launch_bounds__(256) void k2a_feat(const ushortT* __restrict__ guide,
        const float* __restrict__ dw_w, const float* __restrict__ dw_b,
        const float* __restrict__ ln_g, const float* __restrict__ ln_b,
        ushortT* __restrict__ feat) {
    int blk = ((blockIdx.x & 7) << 9) | (blockIdx.x >> 3);   // XCD-chunked bijection (4096)
    int p0 = blk * 8;
    int t = threadIdx.x;
    int px = t >> 5, cg = t & 31, c0 = cg * 8;
    int p = p0 + px;
    int x = p & 63, y = (p >> 6) & 63, b = p >> 12;

    __shared__ float Wl[3072];   // [0,2304) taps, [2304,2560) dw_b, [2560,2816) ln_g, [2816,3072) ln_b
    #pragma unroll
    for (int i = 0; i < 12; ++i) {
        int idx = t + i * 256;
        float w;
        if (idx < 2304)      w = dw_w[idx];
        else if (idx < 2560) w = dw_b[idx - 2304];
        else if (idx < 2816) w = ln_g[idx - 2560];
        else                 w = ln_b[idx - 2816];
        Wl[idx] = w;
    }
    __syncthreads();

    float f[8];
    #pragma unroll
    for (int j = 0; j < 8; ++j) f[j] = Wl[2304 + c0 + j];
    #pragma unroll
    for (int tap = 0; tap < 9; ++tap) {
        int dy = tap / 3 - 1, dx = tap % 3 - 1;
        int yy = y + dy, xx = x + dx;
        if (yy >= 0 && yy < HH && xx >= 0 && xx < WW) {
            short8 v = *(const short8*)(guide + (size_t)((b * HH + yy) * WW + xx) * CC + c0);
            #pragma unroll
            for (int j = 0; j < 8; ++j)
                f[j] = fmaf(b2f((ushortT)v[j]), Wl[tap * CC + c0 + j], f[j]);
        }
    }
    // LayerNorm over C: reduce 8 local + 32 lanes (half-wave owns one pixel)
    float s1 = 0.f, s2 = 0.f;
    #pragma unroll
    for (int j = 0; j < 8; ++j) { s1 += f[j]; s2 += f[j] * f[j]; }
    #pragma unroll
    for (int off = 16; off; off >>= 1) {
        s1 += __shfl_xor(s1, off);
        s2 += __shfl_xor(s2, off);
    }
    float mean = s1 * (1.0f / CC);
    float var  = s2 * (1.0f / CC) - mean * mean;
    float rs = rsqrtf(var + EPSV);
    short8 sv;
    #pragma unroll
    for (int j = 0; j < 8; ++j) {
        float v = (f[j] - mean) * rs * Wl[2560 + c0 + j] + Wl[2816 + c0 + j];
        float u2 = 1.5957691216057308f * (v + 0.044715f * v * v * v);
        v = v * __frcp_rn(1.0f + __expf(-u2));
        sv[j] = (short)f2b(v);
    }
    *(short8*)(feat + (size_t)p * CC + c0) = sv;
}

// ---------------- K2b: offmask = feat @ [off_w|mask_w] + bias, softmax(mask) ----------------
__global__ __launch_bounds__(256) void k2b_heads(const ushortT* __restrict__ feat,
        const float* __restrict__ off_w, const float* __restrict__ off_b,
        const float* __restrict__ mask_w, const float* __restrict__ mask_b,
        float* __restrict__ offmask) {
    int p0 = blockIdx.x * 64;
    int t = threadIdx.x;
    __shared__ float Wc[CC * 32];
    __shared__ float As[64 * 36];

    for (int idx = t; idx < CC * 32; idx += 256) {
        int k = idx >> 5, j = idx & 31;
        float w = 0.f;
        if (j < 18)      w = off_w[k * 18 + j];
        else if (j < 27) w = mask_w[k * 9 + (j - 18)];
        Wc[idx] = w;
    }

    int tx = t & 7, ty = t >> 3;
    int n0 = tx * 4, m0 = ty * 2;
    float acc[2][4] = {};

    for (int k0 = 0; k0 < CC; k0 += 32) {
        {
            int m = t >> 2, kq = (t & 3) * 8;
            short8 v = *(const short8*)(feat + (size_t)(p0 + m) * CC + k0 + kq);
            #pragma unroll
            for (int j = 0; j < 8; ++j)
                As[m * 36 + kq + j] = b2f((ushortT)v[j]);
        }
        __syncthreads();
        #pragma unroll
        for (int kk = 0; kk < 32; ++kk) {
            float a0 = As[m0 * 36 + kk];
            float a1 = As[(m0 + 1) * 36 + kk];
            const float* bp = Wc + (k0 + kk) * 32 + n0;
            #pragma unroll
            for (int ni = 0; ni < 4; ++ni) {
                float bw = bp[ni];
                acc[0][ni] = fmaf(a0, bw, acc[0][ni]);
                acc[1][ni] = fmaf(a1, bw, acc[1][ni]);
            }
        }
        __syncthreads();
    }

    float* O = As;
    #pragma unroll
    for (int ni = 0; ni < 4; ++ni) {
        int j = n0 + ni;
        float bias = (j < 18) ? off_b[j] : ((j < 27) ? mask_b[j - 18] : 0.f);
        O[m0 * 36 + j] = acc[0][ni] + bias;
        O[(m0 + 1) * 36 + j] = acc[1][ni] + bias;
    }
    __syncthreads();
    if (t < 64) {
        float* row = O + t * 36 + 18;
        float mx = row[0];
        #pragma unroll
        for (int k = 1; k < 9; ++k) mx = fmaxf(mx, row[k]);
        float e9[9], ssum = 0.f;
        #pragma unroll
        for (int k = 0; k < 9; ++k) { e9[k] = __expf(row[k] - mx); ssum += e9[k]; }
        float inv = __frcp_rn(ssum);
        #pragma unroll
        for (int k = 0; k < 9; ++k) row[k] = e9[k] * inv;
    }
    __syncthreads();
    #pragma unroll
    for (int i = 0; i < 8; ++i) {
        int idx = t + i * 256;
        int pp = idx >> 5, j = idx & 31;
        offmask[(size_t)(p0 + pp) * 32 + j] = O[pp * 36 + j];
    }
}

// ---------------- K3: xproj(bf16) = x1t @ BTin^T + in_b  [MFMA, 64x64 tiles] ----------------
// grid: 512 Mtiles x 4 Ntiles = 2048 blocks, 256 threads = 4 waves (2x2), BK=64
__global__ __launch_bounds__(256) void k3_mfma(const ushortT* __restrict__ A,
        const ushortT* __restrict__ Bt, const float* __restrict__ bias,
        ushortT* __restrict__ C) {
    __shared__ short Asb[64 * 72];
    __shared__ short Bsb[64 * 72];
    int t = threadIdx.x;
    int m0 = (blockIdx.x >> 2) * 64;
    int n0 = (blockIdx.x & 3) * 64;
    int lane = t & 63, w = t >> 6;
    int wr = w >> 1, wc = w & 1;
    int cl = lane & 15, rg = lane >> 4;

    floatx4 acc[2][2];
    floatx4 zero = {0.f, 0.f, 0.f, 0.f};
    #pragma unroll
    for (int i = 0; i < 2; ++i)
        #pragma unroll
        for (int j = 0; j < 2; ++j) acc[i][j] = zero;

    for (int k0 = 0; k0 < CC; k0 += 64) {
        #pragma unroll
        for (int i = 0; i < 2; ++i) {
            int e = t + i * 256;
            int row = e >> 3, q = e & 7;
            *(short8*)(&Asb[row * 72 + q * 8]) =
                *(const short8*)(A + (size_t)(m0 + row) * CC + k0 + q * 8);
            *(short8*)(&Bsb[row * 72 + q * 8]) =
                *(const short8*)(Bt + (size_t)(n0 + row) * CC + k0 + q * 8);
        }
        __syncthreads();
        #pragma unroll
        for (int kk = 0; kk < 2; ++kk) {
            short8 af[2], bfr[2];
            #pragma unroll
            for (int f = 0; f < 2; ++f) {
                af[f]  = *(const short8*)(&Asb[(wr * 32 + f * 16 + cl) * 72 + kk * 32 + rg * 8]);
                bfr[f] = *(const short8*)(&Bsb[(wc * 32 + f * 16 + cl) * 72 + kk * 32 + rg * 8]);
            }
            #pragma unroll
            for (int fr = 0; fr < 2; ++fr)
                #pragma unroll
                for (int fc = 0; fc < 2; ++fc)
                    acc[fr][fc] = __builtin_amdgcn_mfma_f32_16x16x32_bf16(
                        af[fr], bfr[fc], acc[fr][fc], 0, 0, 0);
        }
        __syncthreads();
    }
    // epilogue: bias + f2b into LDS (reuse Asb), then coalesced short8 stores
    short* Co = Asb;
    #pragma unroll
    for (int fc = 0; fc < 2; ++fc) {
        int n = wc * 32 + fc * 16 + cl;
        float bv = bias[n0 + n];
        #pragma unroll
        for (int fr = 0; fr < 2; ++fr) {
            int mr = wr * 32 + fr * 16 + rg * 4;
            #pragma unroll
            for (int j = 0; j < 4; ++j)
                Co[(mr + j) * 72 + n] = (short)f2b(acc[fr][fc][j] + bv);
        }
    }
    __syncthreads();
    #pragma unroll
    for (int i = 0; i < 2; ++i) {
        int e = t + i * 256;
        int row = e >> 3, q = e & 7;
        *(short8*)(C + (size_t)(m0 + row) * CC + n0 + q * 8) = *(const short8*)(&Co[row * 72 + q * 8]);
    }
}

// ---------------- K4: deformable bilinear sampling (bf16, vectorized) ----------------
// grid: NPIX/8 = 4096 blocks (XCD-swizzled), 256 threads: px = t>>5, cg = t&31 (8 ch each)
__global__ __launch_bounds__(256) void k4_sample(const ushortT* __restrict__ xproj,
        const float* __restrict__ offmask, ushortT* __restrict__ accb) {
    int blk = ((blockIdx.x & 7) << 9) | (blockIdx.x >> 3);
    int p0 = blk * 8;
    int t = threadIdx.x;
    int px = t >> 5, cg = t & 31, c0 = cg * 8;

    __shared__ int   s_idx[8][9][4];
    __shared__ float s_w[8][9][4];
    if (t < 72) {
        int pxi = t / 9, k = t - pxi * 9;
        int p = p0 + pxi;
        int x = p & 63, y = (p >> 6) & 63, b = p >> 12;
        float dx = offmask[(size_t)p * 32 + 2 * k];
        float dy = offmask[(size_t)p * 32 + 2 * k + 1];
        float m  = offmask[(size_t)p * 32 + 18 + k];
        float py = (float)y + (float)(k / 3 - 1) + dy;
        float pxf = (float)x + (float)(k % 3 - 1) + dx;
        float y0f = floorf(py), x0f = floorf(pxf);
        float wy = py - y0f, wx = pxf - x0f;
        int y0 = (int)y0f, x0 = (int)x0f;
        int y1 = y0 + 1, x1 = x0 + 1;
        float vy0 = (y0 >= 0 && y0 < HH) ? 1.f : 0.f;
        float vy1 = (y1 >= 0 && y1 < HH) ? 1.f : 0.f;
        float vx0 = (x0 >= 0 && x0 < WW) ? 1.f : 0.f;
        float vx1 = (x1 >= 0 && x1 < WW) ? 1.f : 0.f;
        int yc0 = max(0, min(HH - 1, y0)), yc1 = max(0, min(HH - 1, y1));
        int xc0 = max(0, min(WW - 1, x0)), xc1 = max(0, min(WW - 1, x1));
        int base = b * HH * WW;
        s_idx[pxi][k][0] = (base + yc0 * WW + xc0) * CC;
        s_idx[pxi][k][1] = (base + yc0 * WW + xc1) * CC;
        s_idx[pxi][k][2] = (base + yc1 * WW + xc0) * CC;
        s_idx[pxi][k][3] = (base + yc1 * WW + xc1) * CC;
        s_w[pxi][k][0] = m * (1.f - wy) * (1.f - wx) * vy0 * vx0;
        s_w[pxi][k][1] = m * (1.f - wy) * wx * vy0 * vx1;
        s_w[pxi][k][2] = m * wy * (1.f - wx) * vy1 * vx0;
        s_w[pxi][k][3] = m * wy * wx * vy1 * vx1;
    }
    __syncthreads();

    float f[8] = {};
    #pragma unroll
    for (int k = 0; k < 9; ++k) {
        #pragma unroll
        for (int cr = 0; cr < 4; ++cr) {
            float wv = s_w[px][k][cr];
            short8 v = *(const short8*)(xproj + s_idx[px][k][cr] + c0);
            #pragma unroll
            for (int j = 0; j < 8; ++j)
                f[j] = fmaf(wv, b2f((ushortT)v[j]), f[j]);
        }
    }
    short8 sv;
    #pragma unroll
    for (int j = 0; j < 8; ++j) sv[j] = (short)f2b(f[j]);
    *(short8*)(accb + (size_t)(p0 + px) * CC + c0) = sv;
}

// ---------------- K5: out = relu(bn(accb @ BTout^T + out_b)) + x1, NCHW  [MFMA, 64x64] ----------
// grid: 2048 blocks, 256 threads
__global__ __launch_bounds__(256) void k5_mfma(const ushortT* __restrict__ A,
        const ushortT* __restrict__ Bt, const float* __restrict__ out_b,
        const float* __restrict__ bn_g, const float* __restrict__ bn_b,
        const float* __restrict__ bn_mean, const float* __restrict__ bn_var,
        const float* __restrict__ x1, float* __restrict__ out) {
    __shared__ __align__(16) char smem[18432];   // Asb|Bsb (2x9216); epilogue reuse: Lo[64][65] f32 (16640)
    short* Asb = (short*)smem;
    short* Bsb = (short*)(smem + 9216);
    float* Lo  = (float*)smem;
    int t = threadIdx.x;
    int bm = blockIdx.x >> 2;
    int m0 = bm * 64;
    int n0 = (blockIdx.x & 3) * 64;
    int lane = t & 63, w = t >> 6;
    int wr = w >> 1, wc = w & 1;
    int cl = lane & 15, rg = lane >> 4;

    floatx4 acc[2][2];
    floatx4 zero = {0.f, 0.f, 0.f, 0.f};
    #pragma unroll
    for (int i = 0; i < 2; ++i)
        #pragma unroll
        for (int j = 0; j < 2; ++j) acc[i][j] = zero;

    for (int k0 = 0; k0 < CC; k0 += 64) {
        #pragma unroll
        for (int i = 0; i < 2; ++i) {
            int e = t + i * 256;
            int row = e >> 3, q = e & 7;
            *(short8*)(&Asb[row * 72 + q * 8]) =
                *(const short8*)(A + (size_t)(m0 + row) * CC + k0 + q * 8);
            *(short8*)(&Bsb[row * 72 + q * 8]) =
                *(const short8*)(Bt + (size_t)(n0 + row) * CC + k0 + q * 8);
        }
        __syncthreads();
        #pragma unroll
        for (int kk = 0; kk < 2; ++kk) {
            short8 af[2], bfr[2];
            #pragma unroll
            for (int f = 0; f < 2; ++f) {
                af[f]  = *(const short8*)(&Asb[(wr * 32 + f * 16 + cl) * 72 + kk * 32 + rg * 8]);
                bfr[f] = *(const short8*)(&Bsb[(wc * 32 + f * 16 + cl) * 72 + kk * 32 + rg * 8]);
            }
            #pragma unroll
            for (int fr = 0; fr < 2; ++fr)
                #pragma unroll
                for (int fc = 0; fc < 2; ++fc)
                    acc[fr][fc] = __builtin_amdgcn_mfma_f32_16x16x32_bf16(
                        af[fr], bfr[fc], acc[fr][fc], 0, 0, 0);
        }
        __syncthreads();
    }

    // epilogue: park raw acc in LDS [pixel][chan], then fused BN+ReLU+residual coalesced NCHW store
    #pragma unroll
    for (int fc = 0; fc < 2; ++fc) {
        int n = wc * 32 + fc * 16 + cl;
        #pragma unroll
        for (int fr = 0; fr < 2; ++fr) {
            int mr = wr * 32 + fr * 16 + rg * 4;
            #pragma unroll
            for (int j = 0; j < 4; ++j)
                Lo[(mr + j) * 65 + n] = acc[fr][fc][j];
        }
    }
    __syncthreads();
    int b = bm >> 6, y = bm & 63;
    #pragma unroll
    for (int i = 0; i < 16; ++i) {
        int e = t + i * 256;                  // 0..4095
        int x = e & 63, cw = e >> 6;          // 64 px x 64 ch
        int co = n0 + cw;
        float val = Lo[x * 65 + cw] + out_b[co];
        float scale = bn_g[co] * rsqrtf(bn_var[co] + EPSV);
        float sh = bn_b[co] - bn_mean[co] * scale;
        val = fmaxf(val * scale + sh, 0.f);
        size_t g = (size_t)((b * CC + co) * HH + y) * WW + x;
        out[g] = val + x1[g];
    }
}

extern "C" void kernel_launch(void* const* d_in, const int* in_sizes, int n_in,
                              void* d_out, int out_size, void* d_ws, size_t ws_size,
                              hipStream_t stream) {
    const float* x1     = (const float*)d_in[0];
    const float* x2     = (const float*)d_in[1];
    const float* dw_w   = (const float*)d_in[2];
    const float* dw_b   = (const float*)d_in[3];
    const float* ln_g   = (const float*)d_in[4];
    const float* ln_b   = (const float*)d_in[5];
    const float* off_w  = (const float*)d_in[6];
    const float* off_b  = (const float*)d_in[7];
    const float* mask_w = (const float*)d_in[8];
    const float* mask_b = (const float*)d_in[9];
    const float* in_w   = (const float*)d_in[10];
    const float* in_b   = (const float*)d_in[11];
    const float* out_w  = (const float*)d_in[12];
    const float* out_b  = (const float*)d_in[13];
    const float* bn_g   = (const float*)d_in[14];
    const float* bn_b   = (const float*)d_in[15];
    const float* bn_mean= (const float*)d_in[16];
    const float* bn_var = (const float*)d_in[17];
    float* out = (float*)d_out;

    char* wsb = (char*)d_ws;
    const size_t SZ = (size_t)NPIX * CC * 2;        // 16.78 MB per bf16 tensor
    ushortT* guide   = (ushortT*)wsb;               // slot0
    ushortT* feat    = (ushortT*)(wsb + SZ);        // slot1
    ushortT* x1t     = (ushortT*)(wsb + 2 * SZ);    // slot2
    float*   offmask = (float*)(wsb + 3 * SZ);      // 4.19 MB
    ushortT* BTin    = (ushortT*)(wsb + 3 * SZ + (size_t)NPIX * 32 * 4);
    ushortT* BTout   = BTin + CC * CC;
    ushortT* xproj   = guide;                       // guide dead after k2a
    ushortT* accb    = feat;                        // feat dead after k2b

    hipLaunchKernelGGL(k0_prep,   dim3(32),   dim3(256), 0, stream, in_w, out_w, BTin, BTout);
    hipLaunchKernelGGL(k1_guide,  dim3(2048), dim3(256), 0, stream, x2, guide);
    hipLaunchKernelGGL(k1t_x1,    dim3(2048), dim3(256), 0, stream, x1, x1t);
    hipLaunchKernelGGL(k2a_feat,  dim3(4096), dim3(256), 0, stream, guide, dw_w, dw_b,
                       ln_g, ln_b, feat);
    hipLaunchKernelGGL(k2b_heads, dim3(512),  dim3(256), 0, stream, feat, off_w, off_b,
                       mask_w, mask_b, offmask);
    hipLaunchKernelGGL(k3_mfma,   dim3(2048), dim3(256), 0, stream, x1t, BTin, in_b, xproj);
    hipLaunchKernelGGL(k4_sample, dim3(4096), dim3(256), 0, stream, xproj, offmask, accb);
    hipLaunchKernelGGL(k5_mfma,   dim3(2048), dim3(256), 0, stream, accb, BTout, out_b,
                       bn_g, bn_b, bn_mean, bn_var, x1, out);
}

// Round 5
// 144.238 us; speedup vs baseline: 3.1557x; 1.0893x over previous
//
#include <hip/hip_runtime.h>
#include <math.h>

#define BB 8
#define CC 256
#define HH 64
#define WW 64
#define H2 32
#define W2 32
#define NPIX (BB*HH*WW)
#define EPSV 1e-5f

typedef unsigned short ushortT;
using short8  = __attribute__((ext_vector_type(8))) short;
using floatx4 = __attribute__((ext_vector_type(4))) float;

__device__ inline float b2f(ushortT u) {
    unsigned int x = ((unsigned int)u) << 16;
    float f; __builtin_memcpy(&f, &x, 4); return f;
}
__device__ inline ushortT f2b(float f) {
    unsigned int x; __builtin_memcpy(&x, &f, 4);
    unsigned int r = x + 0x7fffu + ((x >> 16) & 1u);   // RNE
    return (ushortT)(r >> 16);
}

// ---------------- K0: transpose+convert weights: in_w/out_w [k][n] f32 -> BT [n][k] bf16 ----------
__global__ __launch_bounds__(256) void k0_prep(const float* __restrict__ in_w,
        const float* __restrict__ out_w, ushortT* __restrict__ BTin,
        ushortT* __restrict__ BTout) {
    int blk = blockIdx.x;
    const float* W = (blk < 16) ? in_w : out_w;
    ushortT* D = (blk < 16) ? BTin : BTout;
    int tid = blk & 15;
    int k0 = (tid >> 2) * 64, n0 = (tid & 3) * 64;
    __shared__ ushortT tl[64][72];
    int t = threadIdx.x;
    #pragma unroll
    for (int i = 0; i < 4; ++i) {
        int e = t + i * 256;
        int r = e >> 4;
        int cg = (e & 15) * 4;
        float4 v = *(const float4*)(W + (size_t)(k0 + r) * CC + n0 + cg);
        tl[cg + 0][r] = f2b(v.x); tl[cg + 1][r] = f2b(v.y);
        tl[cg + 2][r] = f2b(v.z); tl[cg + 3][r] = f2b(v.w);
    }
    __syncthreads();
    #pragma unroll
    for (int i = 0; i < 2; ++i) {
        int e = t + i * 256;
        int n = e >> 3, kg = (e & 7) * 8;
        *(short8*)(D + (size_t)(n0 + n) * CC + k0 + kg) = *(const short8*)(&tl[n][kg]);
    }
}

// ---------------- K1: bilinear 2x upsample of x2, |x21-x22| -> guide NHWC bf16 ----------------
__global__ __launch_bounds__(256) void k1_guide(const float* __restrict__ x2,
                                                ushortT* __restrict__ guide) {
    int blk = blockIdx.x;
    int c0 = (blk & 3) * 64;
    int y  = (blk >> 2) & 63;
    int b  = blk >> 8;
    int bb = b & 3;
    __shared__ float tile[64][65];
    int t = threadIdx.x;
    int x = t & 63;

    float sx = 0.5f * x - 0.25f;
    float sy = 0.5f * y - 0.25f;
    float fx0 = floorf(sx), fy0 = floorf(sy);
    float wx = sx - fx0, wy = sy - fy0;
    int jx0 = (int)fx0, jy0 = (int)fy0;
    int ix0 = max(0, min(W2 - 1, jx0));
    int ix1 = max(0, min(W2 - 1, jx0 + 1));
    int iy0 = max(0, min(H2 - 1, jy0));
    int iy1 = max(0, min(H2 - 1, jy0 + 1));
    float w00 = (1.f - wy) * (1.f - wx), w01 = (1.f - wy) * wx;
    float w10 = wy * (1.f - wx), w11 = wy * wx;
    int o00 = iy0 * W2 + ix0, o01 = iy0 * W2 + ix1;
    int o10 = iy1 * W2 + ix0, o11 = iy1 * W2 + ix1;

    int cl = t >> 6;
    #pragma unroll
    for (int it = 0; it < 16; ++it) {
        int c = cl + it * 4;
        const float* p1 = x2 + (size_t)((bb * CC + c0 + c) * H2) * W2;
        const float* p2 = x2 + (size_t)(((bb + 4) * CC + c0 + c) * H2) * W2;
        float v1 = w00 * p1[o00] + w01 * p1[o01] + w10 * p1[o10] + w11 * p1[o11];
        float v2 = w00 * p2[o00] + w01 * p2[o01] + w10 * p2[o10] + w11 * p2[o11];
        tile[c][x] = fabsf(v1 - v2);
    }
    __syncthreads();
    #pragma unroll
    for (int it = 0; it < 16; ++it) {
        int idx = t + it * 256;
        int cw = idx & 63;
        int xw = idx >> 6;
        guide[(size_t)((b * HH + y) * WW + xw) * CC + c0 + cw] = f2b(tile[cw][xw]);
    }
}

// ---------------- K2a: dwconv3x3 + LN + GELU -> feat NHWC bf16 ----------------
// grid: NPIX/8 = 4096 blocks (XCD-swizzled), 256 threads: px = t>>5 (8 px), cg = t&31 (8 ch each)
__global__ __launch_bounds__(256) void k2a_feat(const ushortT* __restrict__ guide,
        const float* __restrict__ dw_w, const float* __restrict__ dw_b,
        const float* __restrict__ ln_g, const float* __restrict__ ln_b,
        ushortT* __restrict__ feat) {
    int blk = ((blockIdx.x & 7) << 9) | (blockIdx.x >> 3);   // XCD-chunked bijection (4096)
    int p0 = blk * 8;
    int t = threadIdx.x;
    int px = t >> 5, cg = t & 31, c0 = cg * 8;
    int p = p0 + px;
    int x = p & 63, y = (p >> 6) & 63, b = p >> 12;

    __shared__ float Wl[3072];   // [0,2304) taps, [2304,2560) dw_b, [2560,2816) ln_g, [2816,3072) ln_b
    #pragma unroll
    for (int i = 0; i < 12; ++i) {
        int idx = t + i * 256;
        float w;
        if (idx < 2304)      w = dw_w[idx];
        else if (idx < 2560) w = dw_b[idx - 2304];
        else if (idx < 2816) w = ln_g[idx - 2560];
        else                 w = ln_b[idx - 2816];
        Wl[idx] = w;
    }
    __syncthreads();

    float f[8];
    #pragma unroll
    for (int j = 0; j < 8; ++j) f[j] = Wl[2304 + c0 + j];
    #pragma unroll
    for (int tap = 0; tap < 9; ++tap) {
        int dy = tap / 3 - 1, dx = tap % 3 - 1;
        int yy = y + dy, xx = x + dx;
        if (yy >= 0 && yy < HH && xx >= 0 && xx < WW) {
            short8 v = *(const short8*)(guide + (size_t)((b * HH + yy) * WW + xx) * CC + c0);
            #pragma unroll
            for (int j = 0; j < 8; ++j)
                f[j] = fmaf(b2f((ushortT)v[j]), Wl[tap * CC + c0 + j], f[j]);
        }
    }
    float s1 = 0.f, s2 = 0.f;
    #pragma unroll
    for (int j = 0; j < 8; ++j) { s1 += f[j]; s2 += f[j] * f[j]; }
    #pragma unroll
    for (int off = 16; off; off >>= 1) {
        s1 += __shfl_xor(s1, off);
        s2 += __shfl_xor(s2, off);
    }
    float mean = s1 * (1.0f / CC);
    float var  = s2 * (1.0f / CC) - mean * mean;
    float rs = rsqrtf(var + EPSV);
    short8 sv;
    #pragma unroll
    for (int j = 0; j < 8; ++j) {
        float v = (f[j] - mean) * rs * Wl[2560 + c0 + j] + Wl[2816 + c0 + j];
        float u2 = 1.5957691216057308f * (v + 0.044715f * v * v * v);
        v = v * __frcp_rn(1.0f + __expf(-u2));
        sv[j] = (short)f2b(v);
    }
    *(short8*)(feat + (size_t)p * CC + c0) = sv;
}

// ---------------- K2b: offmask = feat @ [off_w|mask_w] + bias, softmax(mask) ----------------
__global__ __launch_bounds__(256) void k2b_heads(const ushortT* __restrict__ feat,
        const float* __restrict__ off_w, const float* __restrict__ off_b,
        const float* __restrict__ mask_w, const float* __restrict__ mask_b,
        float* __restrict__ offmask) {
    int p0 = blockIdx.x * 64;
    int t = threadIdx.x;
    __shared__ float Wc[CC * 32];
    __shared__ float As[64 * 36];

    for (int idx = t; idx < CC * 32; idx += 256) {
        int k = idx >> 5, j = idx & 31;
        float w = 0.f;
        if (j < 18)      w = off_w[k * 18 + j];
        else if (j < 27) w = mask_w[k * 9 + (j - 18)];
        Wc[idx] = w;
    }

    int tx = t & 7, ty = t >> 3;
    int n0 = tx * 4, m0 = ty * 2;
    float acc[2][4] = {};

    for (int k0 = 0; k0 < CC; k0 += 32) {
        {
            int m = t >> 2, kq = (t & 3) * 8;
            short8 v = *(const short8*)(feat + (size_t)(p0 + m) * CC + k0 + kq);
            #pragma unroll
            for (int j = 0; j < 8; ++j)
                As[m * 36 + kq + j] = b2f((ushortT)v[j]);
        }
        __syncthreads();
        #pragma unroll
        for (int kk = 0; kk < 32; ++kk) {
            float a0 = As[m0 * 36 + kk];
            float a1 = As[(m0 + 1) * 36 + kk];
            const float* bp = Wc + (k0 + kk) * 32 + n0;
            #pragma unroll
            for (int ni = 0; ni < 4; ++ni) {
                float bw = bp[ni];
                acc[0][ni] = fmaf(a0, bw, acc[0][ni]);
                acc[1][ni] = fmaf(a1, bw, acc[1][ni]);
            }
        }
        __syncthreads();
    }

    float* O = As;
    #pragma unroll
    for (int ni = 0; ni < 4; ++ni) {
        int j = n0 + ni;
        float bias = (j < 18) ? off_b[j] : ((j < 27) ? mask_b[j - 18] : 0.f);
        O[m0 * 36 + j] = acc[0][ni] + bias;
        O[(m0 + 1) * 36 + j] = acc[1][ni] + bias;
    }
    __syncthreads();
    if (t < 64) {
        float* row = O + t * 36 + 18;
        float mx = row[0];
        #pragma unroll
        for (int k = 1; k < 9; ++k) mx = fmaxf(mx, row[k]);
        float e9[9], ssum = 0.f;
        #pragma unroll
        for (int k = 0; k < 9; ++k) { e9[k] = __expf(row[k] - mx); ssum += e9[k]; }
        float inv = __frcp_rn(ssum);
        #pragma unroll
        for (int k = 0; k < 9; ++k) row[k] = e9[k] * inv;
    }
    __syncthreads();
    #pragma unroll
    for (int i = 0; i < 8; ++i) {
        int idx = t + i * 256;
        int pp = idx >> 5, j = idx & 31;
        offmask[(size_t)(p0 + pp) * 32 + j] = O[pp * 36 + j];
    }
}

// ---------------- K3: xproj(bf16) = NHWC(x1) @ BTin^T + in_b  [MFMA, 64x256 tile] ----------------
// grid: 512 M-tiles (XCD-chunked), 256 threads = 4 waves (1x4), BK=64
// A staged straight from NCHW f32 x1 (transpose+convert in LDS) -- k1t fused away.
__global__ __launch_bounds__(256) void k3_mfma(const float* __restrict__ x1,
        const ushortT* __restrict__ Bt, const float* __restrict__ bias,
        ushortT* __restrict__ C) {
    __shared__ __align__(16) char smem[46080];   // Asb[64*72]s | Bsb[256*72]s ; epi: Co[64][264]s
    short* Asb = (short*)smem;
    short* Bsb = (short*)(smem + 9216);
    int t = threadIdx.x;
    int bm = ((blockIdx.x & 7) << 6) | (blockIdx.x >> 3);   // XCD-chunked bijection (512)
    int m0 = bm * 64;
    int b = bm >> 6, y = bm & 63;
    int lane = t & 63, w = t >> 6;
    int cl = lane & 15, rg = lane >> 4;

    floatx4 acc[4][4];
    floatx4 zero = {0.f, 0.f, 0.f, 0.f};
    #pragma unroll
    for (int i = 0; i < 4; ++i)
        #pragma unroll
        for (int j = 0; j < 4; ++j) acc[i][j] = zero;

    for (int k0 = 0; k0 < CC; k0 += 64) {
        // A stage: 64 ch x 64 px from NCHW f32, transposed into Asb[px][ch]
        #pragma unroll
        for (int i = 0; i < 4; ++i) {
            int e = t + i * 256;             // 1024 float4 items
            int ch = e >> 4, x4 = (e & 15) * 4;
            float4 v = *(const float4*)(x1 + (size_t)((b * CC + k0 + ch) * HH + y) * WW + x4);
            Asb[(x4 + 0) * 72 + ch] = (short)f2b(v.x);
            Asb[(x4 + 1) * 72 + ch] = (short)f2b(v.y);
            Asb[(x4 + 2) * 72 + ch] = (short)f2b(v.z);
            Asb[(x4 + 3) * 72 + ch] = (short)f2b(v.w);
        }
        // B stage: 256 n x 64 k
        #pragma unroll
        for (int i = 0; i < 8; ++i) {
            int e = t + i * 256;
            int n = e >> 3, kq = (e & 7) * 8;
            *(short8*)(&Bsb[n * 72 + kq]) =
                *(const short8*)(Bt + (size_t)n * CC + k0 + kq);
        }
        __syncthreads();
        #pragma unroll
        for (int kk = 0; kk < 2; ++kk) {
            short8 af[4], bfr[4];
            #pragma unroll
            for (int f = 0; f < 4; ++f) {
                af[f]  = *(const short8*)(&Asb[(f * 16 + cl) * 72 + kk * 32 + rg * 8]);
                bfr[f] = *(const short8*)(&Bsb[(w * 64 + f * 16 + cl) * 72 + kk * 32 + rg * 8]);
            }
            #pragma unroll
            for (int fr = 0; fr < 4; ++fr)
                #pragma unroll
                for (int fc = 0; fc < 4; ++fc)
                    acc[fr][fc] = __builtin_amdgcn_mfma_f32_16x16x32_bf16(
                        af[fr], bfr[fc], acc[fr][fc], 0, 0, 0);
        }
        __syncthreads();
    }
    // epilogue: bias + f2b into LDS, then coalesced short8 stores (NHWC)
    short* Co = (short*)smem;   // [64][264]
    #pragma unroll
    for (int fc = 0; fc < 4; ++fc) {
        int n = w * 64 + fc * 16 + cl;
        float bv = bias[n];
        #pragma unroll
        for (int fr = 0; fr < 4; ++fr) {
            int mr = fr * 16 + rg * 4;
            #pragma unroll
            for (int j = 0; j < 4; ++j)
                Co[(mr + j) * 264 + n] = (short)f2b(acc[fr][fc][j] + bv);
        }
    }
    __syncthreads();
    #pragma unroll
    for (int i = 0; i < 8; ++i) {
        int e = t + i * 256;
        int px = e >> 5, oct = e & 31;
        *(short8*)(C + (size_t)(m0 + px) * CC + oct * 8) = *(const short8*)(&Co[px * 264 + oct * 8]);
    }
}

// ---------------- K45: fused deformable gather + out-proj GEMM + BN + ReLU + residual ----------
// grid: 512 M-tiles (XCD-chunked), 256 threads = 4 waves, BM=64 px, BN=256, BK=64
__global__ __launch_bounds__(256) void k45_fused(const ushortT* __restrict__ xproj,
        const float* __restrict__ offmask, const ushortT* __restrict__ Bt,
        const float* __restrict__ out_b,
        const float* __restrict__ bn_g, const float* __restrict__ bn_b,
        const float* __restrict__ bn_mean, const float* __restrict__ bn_var,
        const float* __restrict__ x1, float* __restrict__ out) {
    __shared__ __align__(16) char smem[66560];
    short* Asb     = (short*)smem;                   // [64][72]   9216 B
    short* Bsb     = (short*)(smem + 9216);          // [256][72] 36864 B
    float* s_w     = (float*)(smem + 46080);         // [64][9][4] 9216 B
    int*   s_idx   = (int*)(smem + 55296);           // [64][9][4] 9216 B
    float* s_scale = (float*)(smem + 64512);         // [256]      1024 B
    float* s_shift = (float*)(smem + 65536);         // [256]      1024 B
    float* Lo      = (float*)smem;                   // epi reuse: [64][129] f32 = 33024 B

    int t = threadIdx.x;
    int bm = ((blockIdx.x & 7) << 6) | (blockIdx.x >> 3);   // XCD-chunked bijection (512)
    int m0 = bm * 64;
    int b = bm >> 6, y = bm & 63;
    int lane = t & 63, w = t >> 6;
    int cl = lane & 15, rg = lane >> 4;

    // fold bias+BN into scale/shift
    if (t < 256) {
        float scale = bn_g[t] * rsqrtf(bn_var[t] + EPSV);
        s_scale[t] = scale;
        s_shift[t] = out_b[t] * scale + bn_b[t] - bn_mean[t] * scale;
    }
    // stage sampling weights/indices for the 64 pixels (px == x position; y,b fixed)
    for (int e = t; e < 576; e += 256) {
        int px = e / 9, k = e - px * 9;
        int p = m0 + px;
        float dx = offmask[(size_t)p * 32 + 2 * k];
        float dy = offmask[(size_t)p * 32 + 2 * k + 1];
        float m  = offmask[(size_t)p * 32 + 18 + k];
        float py  = (float)y  + (float)(k / 3 - 1) + dy;
        float pxf = (float)px + (float)(k % 3 - 1) + dx;
        float y0f = floorf(py), x0f = floorf(pxf);
        float wy = py - y0f, wx = pxf - x0f;
        int y0 = (int)y0f, x0 = (int)x0f;
        int y1 = y0 + 1, x1i = x0 + 1;
        float vy0 = (y0 >= 0 && y0 < HH) ? 1.f : 0.f;
        float vy1 = (y1 >= 0 && y1 < HH) ? 1.f : 0.f;
        float vx0 = (x0 >= 0 && x0 < WW) ? 1.f : 0.f;
        float vx1 = (x1i >= 0 && x1i < WW) ? 1.f : 0.f;
        int yc0 = max(0, min(HH - 1, y0)), yc1 = max(0, min(HH - 1, y1));
        int xc0 = max(0, min(WW - 1, x0)), xc1 = max(0, min(WW - 1, x1i));
        int base = b * HH * WW;
        int o = (px * 9 + k) * 4;
        s_idx[o + 0] = (base + yc0 * WW + xc0) * CC;
        s_idx[o + 1] = (base + yc0 * WW + xc1) * CC;
        s_idx[o + 2] = (base + yc1 * WW + xc0) * CC;
        s_idx[o + 3] = (base + yc1 * WW + xc1) * CC;
        s_w[o + 0] = m * (1.f - wy) * (1.f - wx) * vy0 * vx0;
        s_w[o + 1] = m * (1.f - wy) * wx * vy0 * vx1;
        s_w[o + 2] = m * wy * (1.f - wx) * vy1 * vx0;
        s_w[o + 3] = m * wy * wx * vy1 * vx1;
    }
    __syncthreads();

    floatx4 acc[4][4];
    floatx4 zero = {0.f, 0.f, 0.f, 0.f};
    #pragma unroll
    for (int i = 0; i < 4; ++i)
        #pragma unroll
        for (int j = 0; j < 4; ++j) acc[i][j] = zero;

    for (int k0 = 0; k0 < CC; k0 += 64) {
        // gather-stage A: 64 px x 64 ch sampled on the fly
        #pragma unroll
        for (int i = 0; i < 2; ++i) {
            int e = t + i * 256;              // 512 items
            int px = e >> 3, o8 = e & 7;
            int c = k0 + o8 * 8;
            const float* wp = s_w  + px * 36;
            const int*   ip = s_idx + px * 36;
            float f[8] = {};
            #pragma unroll
            for (int q = 0; q < 36; ++q) {
                float wv = wp[q];
                short8 v = *(const short8*)(xproj + ip[q] + c);
                #pragma unroll
                for (int j = 0; j < 8; ++j)
                    f[j] = fmaf(wv, b2f((ushortT)v[j]), f[j]);
            }
            short8 sv;
            #pragma unroll
            for (int j = 0; j < 8; ++j) sv[j] = (short)f2b(f[j]);
            *(short8*)(&Asb[px * 72 + o8 * 8]) = sv;
        }
        // B stage: 256 n x 64 k
        #pragma unroll
        for (int i = 0; i < 8; ++i) {
            int e = t + i * 256;
            int n = e >> 3, kq = (e & 7) * 8;
            *(short8*)(&Bsb[n * 72 + kq]) =
                *(const short8*)(Bt + (size_t)n * CC + k0 + kq);
        }
        __syncthreads();
        #pragma unroll
        for (int kk = 0; kk < 2; ++kk) {
            short8 af[4], bfr[4];
            #pragma unroll
            for (int f = 0; f < 4; ++f) {
                af[f]  = *(const short8*)(&Asb[(f * 16 + cl) * 72 + kk * 32 + rg * 8]);
                bfr[f] = *(const short8*)(&Bsb[(w * 64 + f * 16 + cl) * 72 + kk * 32 + rg * 8]);
            }
            #pragma unroll
            for (int fr = 0; fr < 4; ++fr)
                #pragma unroll
                for (int fc = 0; fc < 4; ++fc)
                    acc[fr][fc] = __builtin_amdgcn_mfma_f32_16x16x32_bf16(
                        af[fr], bfr[fc], acc[fr][fc], 0, 0, 0);
        }
        __syncthreads();
    }

    // epilogue: 2 phases of 128 channels; Lo bounce -> fused BN+ReLU+residual NCHW stores
    #pragma unroll
    for (int ph = 0; ph < 2; ++ph) {
        if ((w >> 1) == ph) {
            #pragma unroll
            for (int fc = 0; fc < 4; ++fc) {
                int cloc = (w & 1) * 64 + fc * 16 + cl;
                #pragma unroll
                for (int fr = 0; fr < 4; ++fr) {
                    int mr = fr * 16 + rg * 4;
                    #pragma unroll
                    for (int j = 0; j < 4; ++j)
                        Lo[(mr + j) * 129 + cloc] = acc[fr][fc][j];
                }
            }
        }
        __syncthreads();
        #pragma unroll
        for (int i = 0; i < 32; ++i) {
            int e = t + i * 256;              // 8192 elems
            int x = e & 63, cw = e >> 6;      // 64 px x 128 ch
            int co = ph * 128 + cw;
            float val = Lo[x * 129 + cw] * s_scale[co] + s_shift[co];
            val = fmaxf(val, 0.f);
            size_t g = (size_t)((b * CC + co) * HH + y) * WW + x;
            out[g] = val + x1[g];
        }
        __syncthreads();
    }
}

extern "C" void kernel_launch(void* const* d_in, const int* in_sizes, int n_in,
                              void* d_out, int out_size, void* d_ws, size_t ws_size,
                              hipStream_t stream) {
    const float* x1     = (const float*)d_in[0];
    const float* x2     = (const float*)d_in[1];
    const float* dw_w   = (const float*)d_in[2];
    const float* dw_b   = (const float*)d_in[3];
    const float* ln_g   = (const float*)d_in[4];
    const float* ln_b   = (const float*)d_in[5];
    const float* off_w  = (const float*)d_in[6];
    const float* off_b  = (const float*)d_in[7];
    const float* mask_w = (const float*)d_in[8];
    const float* mask_b = (const float*)d_in[9];
    const float* in_w   = (const float*)d_in[10];
    const float* in_b   = (const float*)d_in[11];
    const float* out_w  = (const float*)d_in[12];
    const float* out_b  = (const float*)d_in[13];
    const float* bn_g   = (const float*)d_in[14];
    const float* bn_b   = (const float*)d_in[15];
    const float* bn_mean= (const float*)d_in[16];
    const float* bn_var = (const float*)d_in[17];
    float* out = (float*)d_out;

    char* wsb = (char*)d_ws;
    const size_t SZ = (size_t)NPIX * CC * 2;        // 16.78 MB per bf16 tensor
    ushortT* guide   = (ushortT*)wsb;               // slot0 (k1 out, k2a in)
    ushortT* feat    = (ushortT*)(wsb + SZ);        // slot1 (k2a out, k2b in)
    float*   offmask = (float*)(wsb + 2 * SZ);      // 4.19 MB
    ushortT* BTin    = (ushortT*)(wsb + 2 * SZ + (size_t)NPIX * 32 * 4);
    ushortT* BTout   = BTin + CC * CC;
    ushortT* xproj   = guide;                       // guide dead after k2a -> alias

    hipLaunchKernelGGL(k0_prep,   dim3(32),   dim3(256), 0, stream, in_w, out_w, BTin, BTout);
    hipLaunchKernelGGL(k1_guide,  dim3(2048), dim3(256), 0, stream, x2, guide);
    hipLaunchKernelGGL(k2a_feat,  dim3(4096), dim3(256), 0, stream, guide, dw_w, dw_b,
                       ln_g, ln_b, feat);
    hipLaunchKernelGGL(k2b_heads, dim3(512),  dim3(256), 0, stream, feat, off_w, off_b,
                       mask_w, mask_b, offmask);
    hipLaunchKernelGGL(k3_mfma,   dim3(512),  dim3(256), 0, stream, x1, BTin, in_b, xproj);
    hipLaunchKernelGGL(k45_fused, dim3(512),  dim3(256), 0, stream, xproj, offmask, BTout,
                       out_b, bn_g, bn_b, bn_mean, bn_var, x1, out);
}